// Round 4
// baseline (507.803 us; speedup 1.0000x reference)
//
#include <hip/hip_runtime.h>
#include <math.h>

#define LEN_IN_C 20197
#define BATCH_C 2
#define BL_C (BATCH_C * LEN_IN_C)   // 40394

typedef short  bf16x8 __attribute__((ext_vector_type(8)));
typedef float  f32x4  __attribute__((ext_vector_type(4)));

__device__ __forceinline__ ushort f2bf(float f) {
    unsigned u = __float_as_uint(f);
    return (ushort)((u + 0x7fffu + ((u >> 16) & 1u)) >> 16);
}
__device__ __forceinline__ float bf2f(ushort u) {
    return __uint_as_float((uint)u << 16);
}
__device__ __forceinline__ uint pkbf(float a, float b) {
    uint r;
    asm("v_cvt_pk_bf16_f32 %0, %1, %2" : "=v"(r) : "v"(a), "v"(b));
    return r;
}
__device__ __forceinline__ void gload16(const void* g, void* l) {
    __builtin_amdgcn_global_load_lds(
        (const __attribute__((address_space(1))) unsigned char*)g,
        (__attribute__((address_space(3))) unsigned char*)l, 16, 0, 0);
}

// ---------------- weight transpose + cast: W (K x N f32) -> WT (N x K bf16) ----------
__global__ __launch_bounds__(256) void transpose_cast(
    const float* __restrict__ W, ushort* __restrict__ WT, int K, int N)
{
    __shared__ float tile[32][33];
    const int n0 = blockIdx.x * 32, k0 = blockIdx.y * 32;
    const int ty = threadIdx.x >> 3, tx = threadIdx.x & 7;
    float4 v = *(const float4*)(W + (size_t)(k0 + ty) * N + n0 + tx * 4);
    tile[ty][tx * 4 + 0] = v.x; tile[ty][tx * 4 + 1] = v.y;
    tile[ty][tx * 4 + 2] = v.z; tile[ty][tx * 4 + 3] = v.w;
    __syncthreads();
    ushort4 o;
    o.x = f2bf(tile[tx * 4 + 0][ty]);
    o.y = f2bf(tile[tx * 4 + 1][ty]);
    o.z = f2bf(tile[tx * 4 + 2][ty]);
    o.w = f2bf(tile[tx * 4 + 3][ty]);
    *(ushort4*)(WT + (size_t)(n0 + ty) * K + k0 + tx * 4) = o;
}

// -------- combined-B builder: BT (640 x 512 bf16) = [[Wv Wo Wa],[0 Wo Wa]]^T --------
__global__ __launch_bounds__(256) void build_comb(
    const float* __restrict__ Wv, const float* __restrict__ Wo,
    const float* __restrict__ Wa, ushort* __restrict__ BT)
{
    const int idx = blockIdx.x * 256 + threadIdx.x;   // 640*128 total
    const int n = idx >> 7, k4 = (idx & 127) * 4;
    ushort4 o;
    ushort* po = (ushort*)&o;
    #pragma unroll
    for (int j = 0; j < 4; ++j) {
        const int k = k4 + j, kk = k & 255;
        float v;
        if (n < 256)      v = (k < 256) ? Wv[(size_t)kk * 256 + n] : 0.f;
        else if (n < 512) v = Wo[(size_t)kk * 256 + (n - 256)];
        else              v = Wa[(size_t)kk * 128 + (n - 512)];
        po[j] = f2bf(v);
    }
    *(ushort4*)(BT + (size_t)n * 512 + k4) = o;
}

__global__ __launch_bounds__(256) void build_bias(
    const float* __restrict__ bv, const float* __restrict__ bo,
    const float* __restrict__ ba, float* __restrict__ out)
{
    const int n = blockIdx.x * 256 + threadIdx.x;
    if (n >= 640) return;
    out[n] = (n < 256) ? bv[n] : (n < 512) ? bo[n - 256] : ba[n - 512];
}

// ---------------- B-stationary MFMA GEMM ----------------
// C(bf16, M x N) = A @ BT^T + bias. Block tile 256 rows x 64 cols, 4 waves
// (wave = 64 rows x 64 cols). B (64 x K) staged in LDS in KC chunks (1-2
// barriers per block TOTAL); A streams global->reg via 4-deep register ring.
// AMODE 0: A bf16 row-major (stride = K). AMODE 3: A = [src f32 | pos f32].
template <int KC, int AMODE, bool RELU>
__global__ __launch_bounds__(256, 2) void gemm_bs(
    const void* __restrict__ Av, const void* __restrict__ A2v,
    const ushort* __restrict__ BT, const float* __restrict__ bias,
    ushort* __restrict__ C, const int M, const int N, const int K,
    const int NT, const int nwg)
{
    constexpr int CPR = KC / 8;               // 16B chunks per LDS row
    constexpr int LOGCPR = (KC == 512) ? 6 : 5;
    constexpr int NCH = 64 * CPR;             // chunks per stage
    constexpr int PT = NCH / 256;             // chunks per thread
    constexpr int NK = KC / 32;               // k-steps per chunk
    __shared__ ushort lsB[64 * KC];

    // bijective XCD chunk swizzle, N-fast within chunk
    const int lid = blockIdx.x;
    const int q = nwg >> 3, r = nwg & 7;
    const int xcd = lid & 7, p = lid >> 3;
    const int nid = (xcd < r ? xcd * (q + 1) : r * (q + 1) + (xcd - r) * q) + p;
    const int nt = nid % NT, mt = nid / NT;
    const int row0 = mt * 256, col0 = nt * 64;

    const int ln = threadIdx.x & 63, wv = threadIdx.x >> 6;
    const int l16 = ln & 15, lk = ln >> 4;

    size_t abase[4];
    #pragma unroll
    for (int m = 0; m < 4; ++m) {
        int rr = row0 + wv * 64 + m * 16 + l16;
        if (rr > M - 1) rr = M - 1;
        abase[m] = (size_t)rr * ((AMODE == 3) ? 256 : K) + lk * 8;
    }

    f32x4 acc[4][4] = {};
    const int nch = K / KC;

    for (int ch = 0; ch < nch; ++ch) {
        const int kc0 = ch * KC;
        if (ch) __syncthreads();
        // ---- stage B chunk: linear LDS dest, inverse-swizzled global source ----
        #pragma unroll
        for (int j = 0; j < PT; ++j) {
            const int d = j * 256 + threadIdx.x;
            const int s = d ^ ((d >> LOGCPR) & 7);
            const int brow = d >> LOGCPR;
            const int k16 = s & (CPR - 1);
            gload16(BT + (size_t)(col0 + brow) * K + kc0 + k16 * 8,
                    (char*)lsB + (size_t)(d & ~63) * 16);
        }
        __syncthreads();

        // ---- barrier-free K-loop over this chunk ----
        if constexpr (AMODE == 0) {
            const ushort* Ab = (const ushort*)Av;
            bf16x8 ar[4][4];                      // [slot][m] ring, depth 4
            #pragma unroll
            for (int s = 0; s < 4; ++s)
                #pragma unroll
                for (int m = 0; m < 4; ++m)
                    ar[s][m] = *(const bf16x8*)(Ab + abase[m] + kc0 + s * 32);
            #pragma unroll
            for (int gs = 0; gs < NK; ++gs) {
                bf16x8 bv[4], av[4];
                #pragma unroll
                for (int n = 0; n < 4; ++n) {
                    const int brow = n * 16 + l16;
                    int byte = (brow * KC + gs * 32 + lk * 8) * 2;
                    byte ^= (brow & 7) << 4;
                    bv[n] = *(const bf16x8*)((const char*)lsB + byte);
                }
                #pragma unroll
                for (int m = 0; m < 4; ++m) av[m] = ar[gs & 3][m];
                if (gs + 4 < NK) {
                    #pragma unroll
                    for (int m = 0; m < 4; ++m)
                        ar[gs & 3][m] = *(const bf16x8*)(Ab + abase[m] + kc0 + (gs + 4) * 32);
                }
                #pragma unroll
                for (int m = 0; m < 4; ++m)
                    #pragma unroll
                    for (int n = 0; n < 4; ++n)
                        acc[m][n] = __builtin_amdgcn_mfma_f32_16x16x32_bf16(
                            bv[n], av[m], acc[m][n], 0, 0, 0);
            }
        } else {
            // fused: K=512 = [src 256 | pos 256], f32, single chunk
            const float* Af = (const float*)Av;
            const float* Ag = (const float*)A2v;
            float4 fr[3][4][2];                   // [slot][m][half], depth 3
            #pragma unroll
            for (int s = 0; s < 3; ++s)
                #pragma unroll
                for (int m = 0; m < 4; ++m) {
                    const float* pp = (s < 8 ? Af : Ag) + abase[m] + (s & 7) * 32;
                    fr[s][m][0] = *(const float4*)pp;
                    fr[s][m][1] = *(const float4*)(pp + 4);
                }
            #pragma unroll
            for (int gs = 0; gs < NK; ++gs) {
                bf16x8 bv[4], av[4];
                #pragma unroll
                for (int n = 0; n < 4; ++n) {
                    const int brow = n * 16 + l16;
                    int byte = (brow * KC + gs * 32 + lk * 8) * 2;
                    byte ^= (brow & 7) << 4;
                    bv[n] = *(const bf16x8*)((const char*)lsB + byte);
                }
                #pragma unroll
                for (int m = 0; m < 4; ++m) {
                    float4 f0 = fr[gs % 3][m][0], f1 = fr[gs % 3][m][1];
                    union { bf16x8 v; uint u[4]; } cv;
                    cv.u[0] = pkbf(f0.x, f0.y); cv.u[1] = pkbf(f0.z, f0.w);
                    cv.u[2] = pkbf(f1.x, f1.y); cv.u[3] = pkbf(f1.z, f1.w);
                    av[m] = cv.v;
                }
                if (gs + 3 < NK) {
                    const int ns = gs + 3;
                    #pragma unroll
                    for (int m = 0; m < 4; ++m) {
                        const float* pp = (ns < 8 ? Af : Ag) + abase[m] + (ns & 7) * 32;
                        fr[gs % 3][m][0] = *(const float4*)pp;
                        fr[gs % 3][m][1] = *(const float4*)(pp + 4);
                    }
                }
                #pragma unroll
                for (int m = 0; m < 4; ++m)
                    #pragma unroll
                    for (int n = 0; n < 4; ++n)
                        acc[m][n] = __builtin_amdgcn_mfma_f32_16x16x32_bf16(
                            bv[n], av[m], acc[m][n], 0, 0, 0);
            }
        }
    }

    // ---- epilogue: lane owns 4 consecutive cols per (m,n) ----
    #pragma unroll
    for (int m = 0; m < 4; ++m) {
        const int grow = row0 + wv * 64 + m * 16 + l16;
        if (grow >= M) continue;
        ushort* crow = C + (size_t)grow * N;
        #pragma unroll
        for (int n = 0; n < 4; ++n) {
            const int col4 = col0 + n * 16 + lk * 4;
            float4 bs = *(const float4*)(bias + col4);
            f32x4 v = acc[m][n];
            float o0 = v[0] + bs.x, o1 = v[1] + bs.y, o2 = v[2] + bs.z, o3 = v[3] + bs.w;
            if (RELU) {
                o0 = fmaxf(o0, 0.f); o1 = fmaxf(o1, 0.f);
                o2 = fmaxf(o2, 0.f); o3 = fmaxf(o3, 0.f);
            }
            *(uint2*)(crow + col4) = make_uint2(pkbf(o0, o1), pkbf(o2, o3));
        }
    }
}

// ---------------- MS-deformable sampling: 1 block = 2 queries ----------------
// comb row layout: [value 256 | off 256 | attn 128] bf16, stride 640.
__global__ __launch_bounds__(256) void sample_kernel(
    const ushort* __restrict__ comb,
    const float* __restrict__ ref,     // (BL, 8)
    ushort* __restrict__ outbf)        // (BL, 256) bf16
{
    constexpr int Hs[4] = {100, 50, 25, 13};
    constexpr int Ws[4] = {152, 76, 38, 19};
    constexpr int St[4] = {0, 15200, 19000, 19950};
    constexpr int NWG = BL_C / 2;      // 20197

    const int orig = blockIdx.x;
    const int qd = NWG / 8, rr = NWG % 8;
    const int xcd = orig & 7, pos = orig >> 3;
    const int blk = (xcd < rr ? xcd * (qd + 1) : rr * (qd + 1) + (xcd - rr) * qd) + pos;
    const int bq0 = blk * 2;

    __shared__ __align__(16) float2 s_iw[2][8][64];

    const int t = threadIdx.x;
    const int qi = t >> 7, r2 = t & 127;
    const int bq = bq0 + qi;
    const int b = (bq >= LEN_IN_C) ? 1 : 0;
    const ushort* crow = comb + (size_t)bq * 640;

    // ---- phase 1: per (h, point): softmax weight + 4 corner (idx, w) ----
    {
        const int h = r2 >> 4, i = r2 & 15, l = i >> 2, p = i & 3;
        float lg = bf2f(crow[512 + h * 16 + i]);
        float mx = lg;
        #pragma unroll
        for (int o = 1; o < 16; o <<= 1) mx = fmaxf(mx, __shfl_xor(mx, o, 16));
        float e = __expf(lg - mx), sm = e;
        #pragma unroll
        for (int o = 1; o < 16; o <<= 1) sm += __shfl_xor(sm, o, 16);
        const float aw = e / sm;

        const uint ov = *(const uint*)(crow + 256 + h * 32 + l * 8 + p * 2);
        const float ox = __uint_as_float(ov << 16);
        const float oy = __uint_as_float(ov & 0xffff0000u);
        const float rx = ref[(size_t)bq * 8 + l * 2 + 0];
        const float ry = ref[(size_t)bq * 8 + l * 2 + 1];
        const int H = Hs[l], W = Ws[l];
        const float x = rx * (float)W + ox - 0.5f;
        const float y = ry * (float)H + oy - 0.5f;
        const float x0f = floorf(x), y0f = floorf(y);
        const float fx = x - x0f, fy = y - y0f;
        const int x0 = (int)x0f, y0 = (int)y0f;
        #pragma unroll
        for (int c = 0; c < 4; ++c) {
            const int dx = c & 1, dy = c >> 1;
            const int xi = x0 + dx, yi = y0 + dy;
            const bool valid = (xi >= 0) & (xi < W) & (yi >= 0) & (yi < H);
            float wgt = (dx ? fx : 1.f - fx) * (dy ? fy : 1.f - fy) * aw;
            if (!valid) wgt = 0.f;
            const int xc = xi < 0 ? 0 : (xi > W - 1 ? W - 1 : xi);
            const int yc = yi < 0 ? 0 : (yi > H - 1 ? H - 1 : yi);
            const int idx = St[l] + yc * W + xc;
            s_iw[qi][h][i * 4 + c] = make_float2(__int_as_float(idx), wgt);
        }
    }
    __syncthreads();

    // ---- phase 2: gather-FMA, 2 channels per thread ----
    const int h2 = r2 >> 4, d2 = r2 & 15;
    const uint* vbase = (const uint*)(comb + (size_t)b * LEN_IN_C * 640 + h2 * 32 + d2 * 2);
    float a0 = 0.f, a1 = 0.f;
    #pragma unroll 8
    for (int j = 0; j < 64; j += 2) {
        float4 iw = *(const float4*)&s_iw[qi][h2][j];
        const int  i0 = __float_as_int(iw.x); const float w0 = iw.y;
        const int  i1 = __float_as_int(iw.z); const float w1 = iw.w;
        const uint v0 = vbase[(size_t)i0 * 320];
        const uint v1 = vbase[(size_t)i1 * 320];
        a0 += w0 * __uint_as_float(v0 << 16);
        a1 += w0 * __uint_as_float(v0 & 0xffff0000u);
        a0 += w1 * __uint_as_float(v1 << 16);
        a1 += w1 * __uint_as_float(v1 & 0xffff0000u);
    }
    const uint o = ((uint)f2bf(a1) << 16) | (uint)f2bf(a0);
    *(uint*)(outbf + (size_t)bq * 256 + h2 * 32 + d2 * 2) = o;
}

// ---------------- fused residual-add + LayerNorm: wave per row ----------------
template <bool ABF, bool OF32>
__global__ __launch_bounds__(256) void add_ln(
    const void* __restrict__ ap, const ushort* __restrict__ bp,
    const float* __restrict__ g, const float* __restrict__ be,
    void* __restrict__ op)
{
    const int row = blockIdx.x * 4 + (threadIdx.x >> 6);
    if (row >= BL_C) return;
    const int ln = threadIdx.x & 63;
    const size_t base = (size_t)row * 256 + ln * 4;

    float x[4];
    if (ABF) {
        ushort4 a4 = *(const ushort4*)((const ushort*)ap + base);
        x[0] = bf2f(a4.x); x[1] = bf2f(a4.y); x[2] = bf2f(a4.z); x[3] = bf2f(a4.w);
    } else {
        float4 a4 = *(const float4*)((const float*)ap + base);
        x[0] = a4.x; x[1] = a4.y; x[2] = a4.z; x[3] = a4.w;
    }
    ushort4 b4 = *(const ushort4*)(bp + base);
    x[0] += bf2f(b4.x); x[1] += bf2f(b4.y); x[2] += bf2f(b4.z); x[3] += bf2f(b4.w);

    float s = x[0] + x[1] + x[2] + x[3];
    #pragma unroll
    for (int o = 32; o >= 1; o >>= 1) s += __shfl_xor(s, o, 64);
    const float mean = s * (1.f / 256.f);
    float d0 = x[0] - mean, d1 = x[1] - mean, d2 = x[2] - mean, d3 = x[3] - mean;
    float ss = d0 * d0 + d1 * d1 + d2 * d2 + d3 * d3;
    #pragma unroll
    for (int o = 32; o >= 1; o >>= 1) ss += __shfl_xor(ss, o, 64);
    const float rs = rsqrtf(ss * (1.f / 256.f) + 1e-5f);

    float4 gv = *(const float4*)(g + ln * 4);
    float4 bv = *(const float4*)(be + ln * 4);
    float o0 = d0 * rs * gv.x + bv.x;
    float o1 = d1 * rs * gv.y + bv.y;
    float o2 = d2 * rs * gv.z + bv.z;
    float o3 = d3 * rs * gv.w + bv.w;

    if (OF32) {
        *(float4*)((float*)op + base) = make_float4(o0, o1, o2, o3);
    } else {
        ushort4 st;
        st.x = f2bf(o0); st.y = f2bf(o1); st.z = f2bf(o2); st.w = f2bf(o3);
        *(ushort4*)((ushort*)op + base) = st;
    }
}

extern "C" void kernel_launch(void* const* d_in, const int* in_sizes, int n_in,
                              void* d_out, int out_size, void* d_ws, size_t ws_size,
                              hipStream_t stream) {
    const float* src    = (const float*)d_in[0];
    const float* pos    = (const float*)d_in[1];
    const float* refpts = (const float*)d_in[2];
    const float* W_off  = (const float*)d_in[5];
    const float* b_off  = (const float*)d_in[6];
    const float* W_attn = (const float*)d_in[7];
    const float* b_attn = (const float*)d_in[8];
    const float* W_val  = (const float*)d_in[9];
    const float* b_val  = (const float*)d_in[10];
    const float* W_out  = (const float*)d_in[11];
    const float* b_out  = (const float*)d_in[12];
    const float* W1     = (const float*)d_in[13];
    const float* b1     = (const float*)d_in[14];
    const float* W2     = (const float*)d_in[15];
    const float* b2     = (const float*)d_in[16];
    const float* g1     = (const float*)d_in[17];
    const float* be1    = (const float*)d_in[18];
    const float* g2     = (const float*)d_in[19];
    const float* be2    = (const float*)d_in[20];
    float* out = (float*)d_out;
    (void)in_sizes; (void)n_in; (void)out_size; (void)ws_size;

    const int BL = BL_C;
    char* ws = (char*)d_ws;
    const size_t COMB_B = (size_t)BL * 640 * 2;
    const size_t HALF_B = (size_t)BL * 256 * 2;
    ushort* comb_bf = (ushort*)(ws);
    ushort* ao_bf   = (ushort*)(ws + COMB_B);
    ushort* src2_bf = (ushort*)(ws + COMB_B + HALF_B);
    ushort* mid_bf  = (ushort*)(ws);                         // overlays comb+ao (dead)
    ushort* x_bf    = (ushort*)(ws + COMB_B + 2 * HALF_B);
    ushort* ffn2_bf = (ushort*)(ws + COMB_B + 3 * HALF_B);
    char*   wts     = ws + COMB_B + 4 * HALF_B;
    ushort* Tcomb = (ushort*)(wts);                          // 640*512
    ushort* Tout  = Tcomb + 640 * 512;                       // 256*256
    ushort* TW1   = Tout + 256 * 256;                        // 1024*256
    ushort* TW2   = TW1 + 1024 * 256;                        // 256*1024
    float*  bcomb = (float*)(TW2 + 256 * 1024);              // 640

    dim3 blk(256);
    const int MT = (BL + 255) / 256;   // 158

    // weight prep
    build_comb<<<dim3(640 * 128 / 256), blk, 0, stream>>>(W_val, W_off, W_attn, Tcomb);
    build_bias<<<dim3(3), blk, 0, stream>>>(b_val, b_off, b_attn, bcomb);
    transpose_cast<<<dim3(8, 8), blk, 0, stream>>>(W_out, Tout, 256, 256);
    transpose_cast<<<dim3(32, 8), blk, 0, stream>>>(W1, TW1, 256, 1024);
    transpose_cast<<<dim3(8, 32), blk, 0, stream>>>(W2, TW2, 1024, 256);

    // [value|off|attn] = [src|pos] @ Tcomb^T + bcomb   (M=BL, N=640, K=512)
    gemm_bs<512, 3, false><<<dim3(MT * 10), blk, 0, stream>>>(
        src, pos, Tcomb, bcomb, comb_bf, BL, 640, 512, 10, MT * 10);

    // deformable sampling -> ao_bf
    sample_kernel<<<dim3(BL / 2), blk, 0, stream>>>(comb_bf, refpts, ao_bf);

    // src2 = ao @ W_out + b_out
    gemm_bs<256, 0, false><<<dim3(MT * 4), blk, 0, stream>>>(
        ao_bf, nullptr, Tout, b_out, src2_bf, BL, 256, 256, 4, MT * 4);

    // x = LN(src + src2) -> bf16
    add_ln<false, false><<<dim3((BL + 3) / 4), blk, 0, stream>>>(src, src2_bf, g1, be1, x_bf);

    // mid = relu(x @ W1 + b1)
    gemm_bs<256, 0, true><<<dim3(MT * 16), blk, 0, stream>>>(
        x_bf, nullptr, TW1, b1, mid_bf, BL, 1024, 256, 16, MT * 16);

    // ffn2 = mid @ W2 + b2
    gemm_bs<512, 0, false><<<dim3(MT * 4), blk, 0, stream>>>(
        mid_bf, nullptr, TW2, b2, ffn2_bf, BL, 256, 1024, 4, MT * 4);

    // out = LN(x + ffn2) -> f32
    add_ln<true, true><<<dim3((BL + 3) / 4), blk, 0, stream>>>(x_bf, ffn2_bf, g2, be2, out);
}

// Round 6
// 345.682 us; speedup vs baseline: 1.4690x; 1.4690x over previous
//
#include <hip/hip_runtime.h>
#include <math.h>

#define LEN_IN_C 20197
#define BATCH_C 2
#define BL_C (BATCH_C * LEN_IN_C)   // 40394

typedef short  bf16x8 __attribute__((ext_vector_type(8)));
typedef float  f32x4  __attribute__((ext_vector_type(4)));

__device__ __forceinline__ ushort f2bf(float f) {
    unsigned u = __float_as_uint(f);
    return (ushort)((u + 0x7fffu + ((u >> 16) & 1u)) >> 16);
}
__device__ __forceinline__ float bf2f(ushort u) {
    return __uint_as_float((uint)u << 16);
}
__device__ __forceinline__ uint pkbf(float a, float b) {
    uint r;
    asm("v_cvt_pk_bf16_f32 %0, %1, %2" : "=v"(r) : "v"(a), "v"(b));
    return r;
}
__device__ __forceinline__ void gload16(const void* g, void* l) {
    __builtin_amdgcn_global_load_lds(
        (const __attribute__((address_space(1))) unsigned char*)g,
        (__attribute__((address_space(3))) unsigned char*)l, 16, 0, 0);
}

// ---------------- prep: q_bf = bf16(src + pos) ----------------
__global__ __launch_bounds__(256) void prep_q(
    const float* __restrict__ src, const float* __restrict__ pos,
    ushort* __restrict__ q, const int n8)
{
    for (int i = blockIdx.x * 256 + threadIdx.x; i < n8; i += gridDim.x * 256) {
        const size_t base = (size_t)i * 8;
        float4 a0 = *(const float4*)(src + base);
        float4 a1 = *(const float4*)(src + base + 4);
        float4 b0 = *(const float4*)(pos + base);
        float4 b1 = *(const float4*)(pos + base + 4);
        uint4 o;
        o.x = pkbf(a0.x + b0.x, a0.y + b0.y);
        o.y = pkbf(a0.z + b0.z, a0.w + b0.w);
        o.z = pkbf(a1.x + b1.x, a1.y + b1.y);
        o.w = pkbf(a1.z + b1.z, a1.w + b1.w);
        *(uint4*)(q + base) = o;
    }
}

// ---------------- weight transpose + cast: W (K x N f32) -> WT (N x K bf16) ----------
__global__ __launch_bounds__(256) void transpose_cast(
    const float* __restrict__ W, ushort* __restrict__ WT, int K, int N)
{
    __shared__ float tile[32][33];
    const int n0 = blockIdx.x * 32, k0 = blockIdx.y * 32;
    const int ty = threadIdx.x >> 3, tx = threadIdx.x & 7;
    float4 v = *(const float4*)(W + (size_t)(k0 + ty) * N + n0 + tx * 4);
    tile[ty][tx * 4 + 0] = v.x; tile[ty][tx * 4 + 1] = v.y;
    tile[ty][tx * 4 + 2] = v.z; tile[ty][tx * 4 + 3] = v.w;
    __syncthreads();
    ushort4 o;
    o.x = f2bf(tile[tx * 4 + 0][ty]);
    o.y = f2bf(tile[tx * 4 + 1][ty]);
    o.z = f2bf(tile[tx * 4 + 2][ty]);
    o.w = f2bf(tile[tx * 4 + 3][ty]);
    *(ushort4*)(WT + (size_t)(n0 + ty) * K + k0 + tx * 4) = o;
}

// -------- Woa^T (384 x 256 bf16): rows 0..255 = Wo cols, 256..383 = Wa cols --------
__global__ __launch_bounds__(256) void build_woa(
    const float* __restrict__ Wo, const float* __restrict__ Wa,
    ushort* __restrict__ T)
{
    const int idx = blockIdx.x * 256 + threadIdx.x;   // 384*64
    if (idx >= 384 * 64) return;
    const int n = idx >> 6, k4 = (idx & 63) * 4;
    ushort4 o; ushort* po = (ushort*)&o;
    #pragma unroll
    for (int j = 0; j < 4; ++j) {
        const int k = k4 + j;
        const float v = (n < 256) ? Wo[(size_t)k * 256 + n] : Wa[(size_t)k * 128 + (n - 256)];
        po[j] = f2bf(v);
    }
    *(ushort4*)(T + (size_t)n * 256 + k4) = o;
}

__global__ __launch_bounds__(256) void build_boa(
    const float* __restrict__ bo, const float* __restrict__ ba,
    float* __restrict__ out)
{
    const int n = blockIdx.x * 256 + threadIdx.x;
    if (n >= 384) return;
    out[n] = (n < 256) ? bo[n] : ba[n - 256];
}

// ---------------- B-stationary MFMA GEMM ----------------
// C(bf16, M x N) = A @ BT^T + bias.  Block = 256 rows x 64 cols, 4 waves
// (each wave 64 rows x 64 cols, shared cols). B staged in LDS in KC=256
// chunks (2 barriers per chunk); A streams global->reg via depth-3 ring.
// AF32: A is f32 (converted on the fly), else bf16. sa = A row stride (elems).
template <bool AF32, bool RELU>
__global__ __launch_bounds__(256) void gemm_bs(
    const void* __restrict__ Av, const ushort* __restrict__ BT,
    const float* __restrict__ bias, ushort* __restrict__ C,
    const int M, const int N, const int K, const int sa,
    const int NT, const int nwg)
{
    __shared__ ushort lsB[64 * 256];   // 32KB

    // bijective XCD chunk swizzle, N-fast within chunk
    const int lid = blockIdx.x;
    const int q = nwg >> 3, r = nwg & 7;
    const int xcd = lid & 7, p = lid >> 3;
    const int nid = (xcd < r ? xcd * (q + 1) : r * (q + 1) + (xcd - r) * q) + p;
    const int nt = nid % NT, mt = nid / NT;
    const int row0 = mt * 256, col0 = nt * 64;

    const int tid = threadIdx.x;
    const int ln = tid & 63, wv = tid >> 6;
    const int l16 = ln & 15, lk = ln >> 4;

    uint abase[4];
    #pragma unroll
    for (int m = 0; m < 4; ++m) {
        int rr = row0 + wv * 64 + m * 16 + l16;
        if (rr > M - 1) rr = M - 1;
        abase[m] = (uint)rr * sa + lk * 8;
    }

    // B fragment LDS addressing: base (row*512 + lk*16) and XOR mask; the XOR
    // must be applied AFTER adding gs*64 (mask covers byte bits 4-6, gs*64
    // touches bit 6 — hoisting the XOR out of the add was round-5's OOB crash).
    uint bbase[4], bxor[4];
    #pragma unroll
    for (int n = 0; n < 4; ++n) {
        const int brow = n * 16 + l16;
        bbase[n] = (uint)(brow * 512 + lk * 16);
        bxor[n]  = (uint)((brow & 7) << 4);
    }

    f32x4 acc[4][4] = {};
    const int nch = K >> 8;

    for (int ch = 0; ch < nch; ++ch) {
        const int kc0 = ch << 8;

        // ---- A ring init (issue early; no LDS dependence) ----
        bf16x8 ar[3][4];
        float4 fr[2][4][2];
        if constexpr (AF32) {
            const float* Af = (const float*)Av;
            #pragma unroll
            for (int s = 0; s < 2; ++s)
                #pragma unroll
                for (int m = 0; m < 4; ++m) {
                    const float* pp = Af + abase[m] + kc0 + s * 32;
                    fr[s][m][0] = *(const float4*)pp;
                    fr[s][m][1] = *(const float4*)(pp + 4);
                }
        } else {
            const ushort* Ab = (const ushort*)Av;
            #pragma unroll
            for (int s = 0; s < 3; ++s)
                #pragma unroll
                for (int m = 0; m < 4; ++m)
                    ar[s][m] = *(const bf16x8*)(Ab + abase[m] + kc0 + s * 32);
        }

        if (ch) __syncthreads();
        // ---- stage B chunk (64 rows x 256 K): linear LDS dest, inv-swizzled src ----
        #pragma unroll
        for (int j = 0; j < 8; ++j) {
            const int d = j * 256 + tid;
            const int brow = d >> 5;
            const int c = (d & 31) ^ (brow & 7);
            gload16(BT + (size_t)(col0 + brow) * K + kc0 + c * 8,
                    (char*)lsB + j * 4096 + wv * 1024);
        }
        __syncthreads();

        // ---- barrier-free K-loop: 8 steps of K=32 ----
        #pragma unroll
        for (int gs = 0; gs < 8; ++gs) {
            bf16x8 bv[4];
            #pragma unroll
            for (int n = 0; n < 4; ++n)
                bv[n] = *(const bf16x8*)((const char*)lsB +
                        ((bbase[n] + gs * 64) ^ bxor[n]));

            bf16x8 av[4];
            if constexpr (AF32) {
                #pragma unroll
                for (int m = 0; m < 4; ++m) {
                    float4 f0 = fr[gs & 1][m][0], f1 = fr[gs & 1][m][1];
                    union { bf16x8 v; uint u[4]; } cv;
                    cv.u[0] = pkbf(f0.x, f0.y); cv.u[1] = pkbf(f0.z, f0.w);
                    cv.u[2] = pkbf(f1.x, f1.y); cv.u[3] = pkbf(f1.z, f1.w);
                    av[m] = cv.v;
                }
                if (gs + 2 < 8) {
                    const float* Af = (const float*)Av;
                    #pragma unroll
                    for (int m = 0; m < 4; ++m) {
                        const float* pp = Af + abase[m] + kc0 + (gs + 2) * 32;
                        fr[gs & 1][m][0] = *(const float4*)pp;
                        fr[gs & 1][m][1] = *(const float4*)(pp + 4);
                    }
                }
            } else {
                #pragma unroll
                for (int m = 0; m < 4; ++m) av[m] = ar[gs % 3][m];
                if (gs + 3 < 8) {
                    const ushort* Ab = (const ushort*)Av;
                    #pragma unroll
                    for (int m = 0; m < 4; ++m)
                        ar[gs % 3][m] = *(const bf16x8*)(Ab + abase[m] + kc0 + (gs + 3) * 32);
                }
            }

            #pragma unroll
            for (int m = 0; m < 4; ++m)
                #pragma unroll
                for (int n = 0; n < 4; ++n)
                    acc[m][n] = __builtin_amdgcn_mfma_f32_16x16x32_bf16(
                        bv[n], av[m], acc[m][n], 0, 0, 0);
        }
    }

    // ---- epilogue: lane owns 4 consecutive cols of one row per (m,n) ----
    #pragma unroll
    for (int m = 0; m < 4; ++m) {
        const int grow = row0 + wv * 64 + m * 16 + l16;
        if (grow >= M) continue;
        ushort* crow = C + (size_t)grow * N;
        #pragma unroll
        for (int n = 0; n < 4; ++n) {
            const int col4 = col0 + n * 16 + lk * 4;
            float4 bs = *(const float4*)(bias + col4);
            f32x4 v = acc[m][n];
            float o0 = v[0] + bs.x, o1 = v[1] + bs.y, o2 = v[2] + bs.z, o3 = v[3] + bs.w;
            if (RELU) {
                o0 = fmaxf(o0, 0.f); o1 = fmaxf(o1, 0.f);
                o2 = fmaxf(o2, 0.f); o3 = fmaxf(o3, 0.f);
            }
            *(uint2*)(crow + col4) = make_uint2(pkbf(o0, o1), pkbf(o2, o3));
        }
    }
}

// ---------------- MS-deformable sampling: 1 block = 2 queries ----------------
__global__ __launch_bounds__(256) void sample_kernel(
    const ushort* __restrict__ value,    // (B, L, 256) bf16
    const ushort* __restrict__ offattn,  // (BL, 384) bf16: [off 256 | attn 128]
    const float* __restrict__ ref,       // (BL, 8)
    ushort* __restrict__ outbf)          // (BL, 256) bf16
{
    constexpr int Hs[4] = {100, 50, 25, 13};
    constexpr int Ws[4] = {152, 76, 38, 19};
    constexpr int St[4] = {0, 15200, 19000, 19950};
    constexpr int NWG = BL_C / 2;      // 20197

    const int orig = blockIdx.x;
    const int qd = NWG / 8, rr = NWG % 8;
    const int xcd = orig & 7, pos = orig >> 3;
    const int blk = (xcd < rr ? xcd * (qd + 1) : rr * (qd + 1) + (xcd - rr) * qd) + pos;
    const int bq0 = blk * 2;

    __shared__ __align__(16) float2 s_iw[2][8][64];

    const int t = threadIdx.x;
    const int qi = t >> 7, r2 = t & 127;
    const int bq = bq0 + qi;
    const int b = (bq >= LEN_IN_C) ? 1 : 0;
    const ushort* crow = offattn + (size_t)bq * 384;

    // ---- phase 1: per (h, point): softmax weight + 4 corner (idx, w) ----
    {
        const int h = r2 >> 4, i = r2 & 15, l = i >> 2, p = i & 3;
        float lg = bf2f(crow[256 + h * 16 + i]);
        float mx = lg;
        #pragma unroll
        for (int o = 1; o < 16; o <<= 1) mx = fmaxf(mx, __shfl_xor(mx, o, 16));
        float e = __expf(lg - mx), sm = e;
        #pragma unroll
        for (int o = 1; o < 16; o <<= 1) sm += __shfl_xor(sm, o, 16);
        const float aw = e / sm;

        const uint ov = *(const uint*)(crow + h * 32 + l * 8 + p * 2);
        const float ox = __uint_as_float(ov << 16);
        const float oy = __uint_as_float(ov & 0xffff0000u);
        const float rx = ref[(size_t)bq * 8 + l * 2 + 0];
        const float ry = ref[(size_t)bq * 8 + l * 2 + 1];
        const int H = Hs[l], W = Ws[l];
        const float x = rx * (float)W + ox - 0.5f;
        const float y = ry * (float)H + oy - 0.5f;
        const float x0f = floorf(x), y0f = floorf(y);
        const float fx = x - x0f, fy = y - y0f;
        const int x0 = (int)x0f, y0 = (int)y0f;
        #pragma unroll
        for (int c = 0; c < 4; ++c) {
            const int dx = c & 1, dy = c >> 1;
            const int xi = x0 + dx, yi = y0 + dy;
            const bool valid = (xi >= 0) & (xi < W) & (yi >= 0) & (yi < H);
            float wgt = (dx ? fx : 1.f - fx) * (dy ? fy : 1.f - fy) * aw;
            if (!valid) wgt = 0.f;
            const int xc = xi < 0 ? 0 : (xi > W - 1 ? W - 1 : xi);
            const int yc = yi < 0 ? 0 : (yi > H - 1 ? H - 1 : yi);
            const int idx = St[l] + yc * W + xc;
            s_iw[qi][h][i * 4 + c] = make_float2(__int_as_float(idx), wgt);
        }
    }
    __syncthreads();

    // ---- phase 2: gather-FMA, 2 channels per thread ----
    const int h2 = r2 >> 4, d2 = r2 & 15;
    const uint* vbase = (const uint*)(value + (size_t)b * LEN_IN_C * 256 + h2 * 32 + d2 * 2);
    float a0 = 0.f, a1 = 0.f;
    #pragma unroll 8
    for (int j = 0; j < 64; j += 2) {
        float4 iw = *(const float4*)&s_iw[qi][h2][j];
        const int  i0 = __float_as_int(iw.x); const float w0 = iw.y;
        const int  i1 = __float_as_int(iw.z); const float w1 = iw.w;
        const uint v0 = vbase[(size_t)i0 * 128];
        const uint v1 = vbase[(size_t)i1 * 128];
        a0 += w0 * __uint_as_float(v0 << 16);
        a1 += w0 * __uint_as_float(v0 & 0xffff0000u);
        a0 += w1 * __uint_as_float(v1 << 16);
        a1 += w1 * __uint_as_float(v1 & 0xffff0000u);
    }
    const uint o = ((uint)f2bf(a1) << 16) | (uint)f2bf(a0);
    *(uint*)(outbf + (size_t)bq * 256 + h2 * 32 + d2 * 2) = o;
}

// ---------------- fused residual-add + LayerNorm: wave per row ----------------
template <bool ABF, bool OF32>
__global__ __launch_bounds__(256) void add_ln(
    const void* __restrict__ ap, const ushort* __restrict__ bp,
    const float* __restrict__ g, const float* __restrict__ be,
    void* __restrict__ op)
{
    const int row = blockIdx.x * 4 + (threadIdx.x >> 6);
    if (row >= BL_C) return;
    const int ln = threadIdx.x & 63;
    const size_t base = (size_t)row * 256 + ln * 4;

    float x[4];
    if (ABF) {
        ushort4 a4 = *(const ushort4*)((const ushort*)ap + base);
        x[0] = bf2f(a4.x); x[1] = bf2f(a4.y); x[2] = bf2f(a4.z); x[3] = bf2f(a4.w);
    } else {
        float4 a4 = *(const float4*)((const float*)ap + base);
        x[0] = a4.x; x[1] = a4.y; x[2] = a4.z; x[3] = a4.w;
    }
    ushort4 b4 = *(const ushort4*)(bp + base);
    x[0] += bf2f(b4.x); x[1] += bf2f(b4.y); x[2] += bf2f(b4.z); x[3] += bf2f(b4.w);

    float s = x[0] + x[1] + x[2] + x[3];
    #pragma unroll
    for (int o = 32; o >= 1; o >>= 1) s += __shfl_xor(s, o, 64);
    const float mean = s * (1.f / 256.f);
    float d0 = x[0] - mean, d1 = x[1] - mean, d2 = x[2] - mean, d3 = x[3] - mean;
    float ss = d0 * d0 + d1 * d1 + d2 * d2 + d3 * d3;
    #pragma unroll
    for (int o = 32; o >= 1; o >>= 1) ss += __shfl_xor(ss, o, 64);
    const float rs = rsqrtf(ss * (1.f / 256.f) + 1e-5f);

    float4 gv = *(const float4*)(g + ln * 4);
    float4 bv = *(const float4*)(be + ln * 4);
    float o0 = d0 * rs * gv.x + bv.x;
    float o1 = d1 * rs * gv.y + bv.y;
    float o2 = d2 * rs * gv.z + bv.z;
    float o3 = d3 * rs * gv.w + bv.w;

    if (OF32) {
        *(float4*)((float*)op + base) = make_float4(o0, o1, o2, o3);
    } else {
        ushort4 st;
        st.x = f2bf(o0); st.y = f2bf(o1); st.z = f2bf(o2); st.w = f2bf(o3);
        *(ushort4*)((ushort*)op + base) = st;
    }
}

extern "C" void kernel_launch(void* const* d_in, const int* in_sizes, int n_in,
                              void* d_out, int out_size, void* d_ws, size_t ws_size,
                              hipStream_t stream) {
    const float* src    = (const float*)d_in[0];
    const float* pos    = (const float*)d_in[1];
    const float* refpts = (const float*)d_in[2];
    const float* W_off  = (const float*)d_in[5];
    const float* b_off  = (const float*)d_in[6];
    const float* W_attn = (const float*)d_in[7];
    const float* b_attn = (const float*)d_in[8];
    const float* W_val  = (const float*)d_in[9];
    const float* b_val  = (const float*)d_in[10];
    const float* W_out  = (const float*)d_in[11];
    const float* b_out  = (const float*)d_in[12];
    const float* W1     = (const float*)d_in[13];
    const float* b1     = (const float*)d_in[14];
    const float* W2     = (const float*)d_in[15];
    const float* b2     = (const float*)d_in[16];
    const float* g1     = (const float*)d_in[17];
    const float* be1    = (const float*)d_in[18];
    const float* g2     = (const float*)d_in[19];
    const float* be2    = (const float*)d_in[20];
    float* out = (float*)d_out;
    (void)in_sizes; (void)n_in; (void)out_size; (void)ws_size;

    const int BL = BL_C;
    char* ws = (char*)d_ws;
    const size_t HB  = (size_t)BL * 256 * 2;     // 20.68 MB
    const size_t OAB = (size_t)BL * 384 * 2;     // 31.02 MB
    const size_t MIDB = (size_t)BL * 1024 * 2;   // 82.73 MB

    ushort* q_bf    = (ushort*)(ws);             // region A (also src2, ffn2 later)
    ushort* src2_bf = (ushort*)(ws);
    ushort* ffn2_bf = (ushort*)(ws);
    ushort* x_bf    = (ushort*)(ws + HB);
    ushort* val_bf  = (ushort*)(ws + 2 * HB);
    ushort* oa_bf   = (ushort*)(ws + 3 * HB);
    ushort* ao_bf   = (ushort*)(ws + 3 * HB + OAB);
    ushort* mid_bf  = (ushort*)(ws + 2 * HB);    // overlays val/oa/ao (dead at G4)
    char*   wts     = ws + 2 * HB + MIDB;
    ushort* Tval = (ushort*)(wts);               // 256x256
    ushort* Toa  = Tval + 256 * 256;             // 384x256
    ushort* Tout = Toa + 384 * 256;              // 256x256
    ushort* TW1  = Tout + 256 * 256;             // 1024x256
    ushort* TW2  = TW1 + 1024 * 256;             // 256x1024
    float*  boa  = (float*)(TW2 + 256 * 1024);   // 384

    dim3 blk(256);
    const int MT = (BL + 255) / 256;   // 158

    // ---- prep ----
    prep_q<<<dim3(2048), blk, 0, stream>>>(src, pos, q_bf, BL * 32);
    transpose_cast<<<dim3(8, 8), blk, 0, stream>>>(W_val, Tval, 256, 256);
    build_woa<<<dim3(96), blk, 0, stream>>>(W_off, W_attn, Toa);
    build_boa<<<dim3(2), blk, 0, stream>>>(b_off, b_attn, boa);
    transpose_cast<<<dim3(8, 8), blk, 0, stream>>>(W_out, Tout, 256, 256);
    transpose_cast<<<dim3(32, 8), blk, 0, stream>>>(W1, TW1, 256, 1024);
    transpose_cast<<<dim3(8, 32), blk, 0, stream>>>(W2, TW2, 1024, 256);

    // G1: value = src @ Wv + bv   (A f32)
    gemm_bs<true, false><<<dim3(MT * 4), blk, 0, stream>>>(
        src, Tval, b_val, val_bf, BL, 256, 256, 256, 4, MT * 4);
    // G2: [off|attn] = q @ [Wo|Wa] + [bo|ba]
    gemm_bs<false, false><<<dim3(MT * 6), blk, 0, stream>>>(
        q_bf, Toa, boa, oa_bf, BL, 384, 256, 256, 6, MT * 6);

    // sampling -> ao
    sample_kernel<<<dim3(BL / 2), blk, 0, stream>>>(val_bf, oa_bf, refpts, ao_bf);

    // G3: src2 = ao @ W_out + b_out  (region A; q dead)
    gemm_bs<false, false><<<dim3(MT * 4), blk, 0, stream>>>(
        ao_bf, Tout, b_out, src2_bf, BL, 256, 256, 256, 4, MT * 4);

    // x = LN(src + src2)
    add_ln<false, false><<<dim3((BL + 3) / 4), blk, 0, stream>>>(src, src2_bf, g1, be1, x_bf);

    // G4: mid = relu(x @ W1 + b1)   (mid overlays val/oa/ao)
    gemm_bs<false, true><<<dim3(MT * 16), blk, 0, stream>>>(
        x_bf, TW1, b1, mid_bf, BL, 1024, 256, 256, 16, MT * 16);

    // G5: ffn2 = mid @ W2 + b2  (region A; src2 dead)
    gemm_bs<false, false><<<dim3(MT * 4), blk, 0, stream>>>(
        mid_bf, TW2, b2, ffn2_bf, BL, 256, 1024, 1024, 4, MT * 4);

    // out = LN(x + ffn2) -> f32
    add_ln<true, true><<<dim3((BL + 3) / 4), blk, 0, stream>>>(x_bf, ffn2_bf, g2, be2, out);
}

// Round 7
// 313.869 us; speedup vs baseline: 1.6179x; 1.1014x over previous
//
#include <hip/hip_runtime.h>
#include <math.h>

#define LEN_IN_C 20197
#define BATCH_C 2
#define BL_C (BATCH_C * LEN_IN_C)   // 40394

typedef short  bf16x8 __attribute__((ext_vector_type(8)));
typedef float  f32x4  __attribute__((ext_vector_type(4)));

__device__ __forceinline__ ushort f2bf(float f) {
    unsigned u = __float_as_uint(f);
    return (ushort)((u + 0x7fffu + ((u >> 16) & 1u)) >> 16);
}
__device__ __forceinline__ float bf2f(ushort u) {
    return __uint_as_float((uint)u << 16);
}
__device__ __forceinline__ uint pkbf(float a, float b) {
    uint r;
    asm("v_cvt_pk_bf16_f32 %0, %1, %2" : "=v"(r) : "v"(a), "v"(b));
    return r;
}
__device__ __forceinline__ void gload16(const void* g, void* l) {
    __builtin_amdgcn_global_load_lds(
        (const __attribute__((address_space(1))) unsigned char*)g,
        (__attribute__((address_space(3))) unsigned char*)l, 16, 0, 0);
}
__device__ __forceinline__ int xcd_swz(int lid, int nwg) {
    const int q = nwg >> 3, r = nwg & 7;
    const int xcd = lid & 7, p = lid >> 3;
    return (xcd < r ? xcd * (q + 1) : r * (q + 1) + (xcd - r) * q) + p;
}

// ================= combined prep kernel (weights + q) =================
__device__ __forceinline__ void tcast32(
    const float* W, ushort* WT, int K, int N, int n0, int k0, float* tile /*32*33*/)
{
    const int ty = threadIdx.x >> 3, tx = threadIdx.x & 7;
    float4 v = *(const float4*)(W + (size_t)(k0 + ty) * N + n0 + tx * 4);
    tile[ty * 33 + tx * 4 + 0] = v.x; tile[ty * 33 + tx * 4 + 1] = v.y;
    tile[ty * 33 + tx * 4 + 2] = v.z; tile[ty * 33 + tx * 4 + 3] = v.w;
    __syncthreads();
    ushort4 o;
    o.x = f2bf(tile[(tx * 4 + 0) * 33 + ty]);
    o.y = f2bf(tile[(tx * 4 + 1) * 33 + ty]);
    o.z = f2bf(tile[(tx * 4 + 2) * 33 + ty]);
    o.w = f2bf(tile[(tx * 4 + 3) * 33 + ty]);
    *(ushort4*)(WT + (size_t)(n0 + ty) * K + k0 + tx * 4) = o;
}

__global__ __launch_bounds__(256) void prep_all(
    const float* __restrict__ src, const float* __restrict__ pos,
    const float* __restrict__ Wv, const float* __restrict__ Wo,
    const float* __restrict__ Wa, const float* __restrict__ Wout,
    const float* __restrict__ W1, const float* __restrict__ W2,
    const float* __restrict__ bo, const float* __restrict__ ba,
    ushort* __restrict__ Tval, ushort* __restrict__ Toa,
    ushort* __restrict__ Tout, ushort* __restrict__ TW1,
    ushort* __restrict__ TW2, float* __restrict__ boa,
    ushort* __restrict__ qout)
{
    __shared__ float tile[32 * 33];
    const int bx = blockIdx.x;
    const int tid = threadIdx.x;
    if (bx < 64) {                       // Tval: 256x256
        tcast32(Wv, Tval, 256, 256, (bx & 7) * 32, (bx >> 3) * 32, tile);
    } else if (bx < 128) {               // Tout
        const int s = bx - 64;
        tcast32(Wout, Tout, 256, 256, (s & 7) * 32, (s >> 3) * 32, tile);
    } else if (bx < 384) {               // TW1: K=256 N=1024
        const int s = bx - 128;
        tcast32(W1, TW1, 256, 1024, (s & 31) * 32, (s >> 5) * 32, tile);
    } else if (bx < 640) {               // TW2: K=1024 N=256
        const int s = bx - 384;
        tcast32(W2, TW2, 1024, 256, (s & 7) * 32, (s >> 3) * 32, tile);
    } else if (bx < 736) {               // build_woa: 384x64 ushort4 tasks
        const int idx = (bx - 640) * 256 + tid;
        const int n = idx >> 6, k4 = (idx & 63) * 4;
        ushort4 o; ushort* po = (ushort*)&o;
        #pragma unroll
        for (int j = 0; j < 4; ++j) {
            const int k = k4 + j;
            const float v = (n < 256) ? Wo[(size_t)k * 256 + n]
                                      : Wa[(size_t)k * 128 + (n - 256)];
            po[j] = f2bf(v);
        }
        *(ushort4*)(Toa + (size_t)n * 256 + k4) = o;
    } else if (bx < 738) {               // boa
        const int n = (bx - 736) * 256 + tid;
        if (n < 384) boa[n] = (n < 256) ? bo[n] : ba[n - 256];
    } else {                             // prep_q grid-stride
        const int n8 = BL_C * 32;
        for (int i = (bx - 738) * 256 + tid; i < n8; i += 1024 * 256) {
            const size_t base = (size_t)i * 8;
            float4 a0 = *(const float4*)(src + base);
            float4 a1 = *(const float4*)(src + base + 4);
            float4 b0 = *(const float4*)(pos + base);
            float4 b1 = *(const float4*)(pos + base + 4);
            uint4 o;
            o.x = pkbf(a0.x + b0.x, a0.y + b0.y);
            o.y = pkbf(a0.z + b0.z, a0.w + b0.w);
            o.z = pkbf(a1.x + b1.x, a1.y + b1.y);
            o.w = pkbf(a1.z + b1.z, a1.w + b1.w);
            *(uint4*)(qout + base) = o;
        }
    }
}

// ================= B-stationary MFMA GEMM (round-6 proven) =================
template <bool AF32, bool RELU>
__global__ __launch_bounds__(256) void gemm_bs(
    const void* __restrict__ Av, const ushort* __restrict__ BT,
    const float* __restrict__ bias, ushort* __restrict__ C,
    const int M, const int N, const int K, const int sa,
    const int NT, const int nwg)
{
    __shared__ ushort lsB[64 * 256];   // 32KB

    const int nid = xcd_swz(blockIdx.x, nwg);
    const int nt = nid % NT, mt = nid / NT;
    const int row0 = mt * 256, col0 = nt * 64;

    const int tid = threadIdx.x;
    const int ln = tid & 63, wv = tid >> 6;
    const int l16 = ln & 15, lk = ln >> 4;

    uint abase[4];
    #pragma unroll
    for (int m = 0; m < 4; ++m) {
        int rr = row0 + wv * 64 + m * 16 + l16;
        if (rr > M - 1) rr = M - 1;
        abase[m] = (uint)rr * sa + lk * 8;
    }
    uint bbase[4], bxor[4];
    #pragma unroll
    for (int n = 0; n < 4; ++n) {
        const int brow = n * 16 + l16;
        bbase[n] = (uint)(brow * 512 + lk * 16);
        bxor[n]  = (uint)((brow & 7) << 4);
    }

    f32x4 acc[4][4] = {};
    const int nch = K >> 8;

    for (int ch = 0; ch < nch; ++ch) {
        const int kc0 = ch << 8;
        bf16x8 ar[3][4];
        float4 fr[2][4][2];
        if constexpr (AF32) {
            const float* Af = (const float*)Av;
            #pragma unroll
            for (int s = 0; s < 2; ++s)
                #pragma unroll
                for (int m = 0; m < 4; ++m) {
                    const float* pp = Af + abase[m] + kc0 + s * 32;
                    fr[s][m][0] = *(const float4*)pp;
                    fr[s][m][1] = *(const float4*)(pp + 4);
                }
        } else {
            const ushort* Ab = (const ushort*)Av;
            #pragma unroll
            for (int s = 0; s < 3; ++s)
                #pragma unroll
                for (int m = 0; m < 4; ++m)
                    ar[s][m] = *(const bf16x8*)(Ab + abase[m] + kc0 + s * 32);
        }

        if (ch) __syncthreads();
        #pragma unroll
        for (int j = 0; j < 8; ++j) {
            const int d = j * 256 + tid;
            const int brow = d >> 5;
            const int c = (d & 31) ^ (brow & 7);
            gload16(BT + (size_t)(col0 + brow) * K + kc0 + c * 8,
                    (char*)lsB + j * 4096 + wv * 1024);
        }
        __syncthreads();

        #pragma unroll
        for (int gs = 0; gs < 8; ++gs) {
            bf16x8 bv[4];
            #pragma unroll
            for (int n = 0; n < 4; ++n)
                bv[n] = *(const bf16x8*)((const char*)lsB +
                        ((bbase[n] + gs * 64) ^ bxor[n]));

            bf16x8 av[4];
            if constexpr (AF32) {
                #pragma unroll
                for (int m = 0; m < 4; ++m) {
                    float4 f0 = fr[gs & 1][m][0], f1 = fr[gs & 1][m][1];
                    union { bf16x8 v; uint u[4]; } cv;
                    cv.u[0] = pkbf(f0.x, f0.y); cv.u[1] = pkbf(f0.z, f0.w);
                    cv.u[2] = pkbf(f1.x, f1.y); cv.u[3] = pkbf(f1.z, f1.w);
                    av[m] = cv.v;
                }
                if (gs + 2 < 8) {
                    const float* Af = (const float*)Av;
                    #pragma unroll
                    for (int m = 0; m < 4; ++m) {
                        const float* pp = Af + abase[m] + kc0 + (gs + 2) * 32;
                        fr[gs & 1][m][0] = *(const float4*)pp;
                        fr[gs & 1][m][1] = *(const float4*)(pp + 4);
                    }
                }
            } else {
                #pragma unroll
                for (int m = 0; m < 4; ++m) av[m] = ar[gs % 3][m];
                if (gs + 3 < 8) {
                    const ushort* Ab = (const ushort*)Av;
                    #pragma unroll
                    for (int m = 0; m < 4; ++m)
                        ar[gs % 3][m] = *(const bf16x8*)(Ab + abase[m] + kc0 + (gs + 3) * 32);
                }
            }

            #pragma unroll
            for (int m = 0; m < 4; ++m)
                #pragma unroll
                for (int n = 0; n < 4; ++n)
                    acc[m][n] = __builtin_amdgcn_mfma_f32_16x16x32_bf16(
                        bv[n], av[m], acc[m][n], 0, 0, 0);
        }
    }

    #pragma unroll
    for (int m = 0; m < 4; ++m) {
        const int grow = row0 + wv * 64 + m * 16 + l16;
        if (grow >= M) continue;
        ushort* crow = C + (size_t)grow * N;
        #pragma unroll
        for (int n = 0; n < 4; ++n) {
            const int col4 = col0 + n * 16 + lk * 4;
            float4 bs = *(const float4*)(bias + col4);
            f32x4 v = acc[m][n];
            float o0 = v[0] + bs.x, o1 = v[1] + bs.y, o2 = v[2] + bs.z, o3 = v[3] + bs.w;
            if (RELU) {
                o0 = fmaxf(o0, 0.f); o1 = fmaxf(o1, 0.f);
                o2 = fmaxf(o2, 0.f); o3 = fmaxf(o3, 0.f);
            }
            *(uint2*)(crow + col4) = make_uint2(pkbf(o0, o1), pkbf(o2, o3));
        }
    }
}

// ============ full-width GEMM (N=256) with fused residual-add + LayerNorm ============
// Block = 64 rows x 256 cols, 4 waves side by side. B double-buffered in LDS
// (KC=64 chunks). A streams via depth-4 register ring.
template <int K, bool RESF32, bool OUTF32>
__global__ __launch_bounds__(256) void gemm_ln(
    const ushort* __restrict__ A, const ushort* __restrict__ BT,
    const float* __restrict__ bias, const void* __restrict__ res,
    const float* __restrict__ g, const float* __restrict__ be,
    void* __restrict__ outp, const int nwg)
{
    __shared__ ushort lsB[2][64 * 256];     // 2 x 32KB
    __shared__ float2 red[4][64];
    constexpr int GST = K / 32;
    constexpr int NCH = K / 64;
    constexpr int M = BL_C;

    const int row0 = xcd_swz(blockIdx.x, nwg) * 64;
    const int tid = threadIdx.x;
    const int ln = tid & 63, wv = tid >> 6;
    const int l16 = ln & 15, lk = ln >> 4;

    uint abase[4];
    #pragma unroll
    for (int m = 0; m < 4; ++m) {
        int rr = row0 + m * 16 + l16;
        if (rr > M - 1) rr = M - 1;
        abase[m] = (uint)rr * K + lk * 8;
    }
    uint bb[4], bx[4];
    #pragma unroll
    for (int n = 0; n < 4; ++n) {
        const int brow = wv * 64 + n * 16 + l16;
        bb[n] = (uint)(brow * 128 + lk * 16);
        bx[n] = (uint)((brow & 7) << 4);
    }

    f32x4 acc[4][4] = {};
    bf16x8 ar[4][4];
    #pragma unroll
    for (int s = 0; s < 4; ++s)
        #pragma unroll
        for (int m = 0; m < 4; ++m)
            ar[s][m] = *(const bf16x8*)(A + abase[m] + s * 32);

    // stage chunk 0 into buf 0
    #pragma unroll
    for (int j = 0; j < 8; ++j) {
        const int d = j * 256 + tid;
        const int brow = d >> 3;
        const int cs = (d & 7) ^ (brow & 7);
        gload16(BT + (size_t)brow * K + cs * 8, (char*)lsB + d * 16);
    }
    __syncthreads();

    for (int c = 0; c < NCH; ++c) {
        if (c + 1 < NCH) {
            const int kc = (c + 1) * 64;
            const uint bo = (uint)((c + 1) & 1) * 32768u;
            #pragma unroll
            for (int j = 0; j < 8; ++j) {
                const int d = j * 256 + tid;
                const int brow = d >> 3;
                const int cs = (d & 7) ^ (brow & 7);
                gload16(BT + (size_t)brow * K + kc + cs * 8,
                        (char*)lsB + bo + d * 16);
            }
        }
        const uint bufo = (uint)(c & 1) * 32768u;
        #pragma unroll
        for (int g2 = 0; g2 < 2; ++g2) {
            const int gs = c * 2 + g2;
            bf16x8 bv[4];
            #pragma unroll
            for (int n = 0; n < 4; ++n)
                bv[n] = *(const bf16x8*)((const char*)lsB + bufo +
                        ((bb[n] + g2 * 64) ^ bx[n]));
            bf16x8 av[4];
            #pragma unroll
            for (int m = 0; m < 4; ++m) av[m] = ar[gs & 3][m];
            if (gs + 4 < GST) {
                #pragma unroll
                for (int m = 0; m < 4; ++m)
                    ar[gs & 3][m] = *(const bf16x8*)(A + abase[m] + (gs + 4) * 32);
            }
            #pragma unroll
            for (int m = 0; m < 4; ++m)
                #pragma unroll
                for (int n = 0; n < 4; ++n)
                    acc[m][n] = __builtin_amdgcn_mfma_f32_16x16x32_bf16(
                        bv[n], av[m], acc[m][n], 0, 0, 0);
        }
        __syncthreads();
    }

    // ---- epilogue: t = acc + bias + residual, then row LN over 256 cols ----
    float4 bias4[4];
    #pragma unroll
    for (int n = 0; n < 4; ++n)
        bias4[n] = *(const float4*)(bias + wv * 64 + n * 16 + lk * 4);

    #pragma unroll
    for (int m = 0; m < 4; ++m) {
        int rowc = row0 + m * 16 + l16; if (rowc > M - 1) rowc = M - 1;
        #pragma unroll
        for (int n = 0; n < 4; ++n) {
            const int col4 = wv * 64 + n * 16 + lk * 4;
            float r0, r1, r2, r3;
            if (RESF32) {
                float4 r4 = *(const float4*)((const float*)res + (size_t)rowc * 256 + col4);
                r0 = r4.x; r1 = r4.y; r2 = r4.z; r3 = r4.w;
            } else {
                ushort4 r4 = *(const ushort4*)((const ushort*)res + (size_t)rowc * 256 + col4);
                r0 = bf2f(r4.x); r1 = bf2f(r4.y); r2 = bf2f(r4.z); r3 = bf2f(r4.w);
            }
            acc[m][n][0] += bias4[n].x + r0;
            acc[m][n][1] += bias4[n].y + r1;
            acc[m][n][2] += bias4[n].z + r2;
            acc[m][n][3] += bias4[n].w + r3;
        }
    }
    #pragma unroll
    for (int m = 0; m < 4; ++m) {
        float s = 0.f, ss = 0.f;
        #pragma unroll
        for (int n = 0; n < 4; ++n)
            #pragma unroll
            for (int j = 0; j < 4; ++j) {
                const float v = acc[m][n][j];
                s += v; ss += v * v;
            }
        s += __shfl_xor(s, 16, 64);  ss += __shfl_xor(ss, 16, 64);
        s += __shfl_xor(s, 32, 64);  ss += __shfl_xor(ss, 32, 64);
        if (lk == 0) red[wv][m * 16 + l16] = make_float2(s, ss);
    }
    __syncthreads();

    float4 g4[4], be4[4];
    #pragma unroll
    for (int n = 0; n < 4; ++n) {
        g4[n]  = *(const float4*)(g  + wv * 64 + n * 16 + lk * 4);
        be4[n] = *(const float4*)(be + wv * 64 + n * 16 + lk * 4);
    }
    #pragma unroll
    for (int m = 0; m < 4; ++m) {
        const int row = row0 + m * 16 + l16;
        const int rr = m * 16 + l16;
        float2 t0 = red[0][rr], t1 = red[1][rr], t2 = red[2][rr], t3 = red[3][rr];
        const float S  = t0.x + t1.x + t2.x + t3.x;
        const float SS = t0.y + t1.y + t2.y + t3.y;
        const float mean = S * (1.f / 256.f);
        float var = SS * (1.f / 256.f) - mean * mean;
        var = fmaxf(var, 0.f);
        const float rs = rsqrtf(var + 1e-5f);
        if (row >= M) continue;
        #pragma unroll
        for (int n = 0; n < 4; ++n) {
            const int col4 = wv * 64 + n * 16 + lk * 4;
            float o0 = (acc[m][n][0] - mean) * rs * g4[n].x + be4[n].x;
            float o1 = (acc[m][n][1] - mean) * rs * g4[n].y + be4[n].y;
            float o2 = (acc[m][n][2] - mean) * rs * g4[n].z + be4[n].z;
            float o3 = (acc[m][n][3] - mean) * rs * g4[n].w + be4[n].w;
            if (OUTF32) {
                *(float4*)((float*)outp + (size_t)row * 256 + col4) =
                    make_float4(o0, o1, o2, o3);
            } else {
                *(uint2*)((ushort*)outp + (size_t)row * 256 + col4) =
                    make_uint2(pkbf(o0, o1), pkbf(o2, o3));
            }
        }
    }
}

// ================= MS-deformable sampling: 1 block = 8 queries =================
__global__ __launch_bounds__(256) void sample_kernel(
    const ushort* __restrict__ value,    // (B, L, 256) bf16
    const ushort* __restrict__ oa,       // (BL, 384) bf16: [off 256 | attn 128]
    const float* __restrict__ ref,       // (BL, 8)
    ushort* __restrict__ outbf)          // (BL, 256) bf16
{
    constexpr int Hs[4] = {100, 50, 25, 13};
    constexpr int Ws[4] = {152, 76, 38, 19};
    constexpr int St[4] = {0, 15200, 19000, 19950};
    constexpr int NWG = (BL_C + 7) / 8;    // 5050

    const int bq0 = xcd_swz(blockIdx.x, NWG) * 8;
    const int t = threadIdx.x;

    __shared__ uint2 s_ow[8][8][65];

    // ---- phase 1: 4 rounds x 2 queries ----
    #pragma unroll
    for (int rnd = 0; rnd < 4; ++rnd) {
        const int qi2 = t >> 7, r2 = t & 127;
        const int qloc = rnd * 2 + qi2;
        int bq = bq0 + qloc; if (bq > BL_C - 1) bq = BL_C - 1;
        const int b = (bq >= LEN_IN_C) ? 1 : 0;
        const int h = r2 >> 4, i = r2 & 15, l = i >> 2, p = i & 3;
        const ushort* crow = oa + (size_t)bq * 384;

        float lg = bf2f(crow[256 + h * 16 + i]);
        float mx = lg;
        #pragma unroll
        for (int o = 1; o < 16; o <<= 1) mx = fmaxf(mx, __shfl_xor(mx, o, 16));
        float e = __expf(lg - mx), sm = e;
        #pragma unroll
        for (int o = 1; o < 16; o <<= 1) sm += __shfl_xor(sm, o, 16);
        const float aw = e / sm;

        const uint ov = *(const uint*)(crow + h * 32 + l * 8 + p * 2);
        const float ox = __uint_as_float(ov << 16);
        const float oy = __uint_as_float(ov & 0xffff0000u);
        const float2 rxy = *(const float2*)(ref + (size_t)bq * 8 + l * 2);
        const int H = Hs[l], W = Ws[l];
        const float x = rxy.x * (float)W + ox - 0.5f;
        const float y = rxy.y * (float)H + oy - 0.5f;
        const float x0f = floorf(x), y0f = floorf(y);
        const float fx = x - x0f, fy = y - y0f;
        const int x0 = (int)x0f, y0 = (int)y0f;
        const uint rowb = (uint)(b * LEN_IN_C + St[l]);
        #pragma unroll
        for (int c = 0; c < 4; ++c) {
            const int dx = c & 1, dy = c >> 1;
            const int xi = x0 + dx, yi = y0 + dy;
            const bool valid = (xi >= 0) & (xi < W) & (yi >= 0) & (yi < H);
            float wgt = (dx ? fx : 1.f - fx) * (dy ? fy : 1.f - fy) * aw;
            if (!valid) wgt = 0.f;
            const int xc = xi < 0 ? 0 : (xi > W - 1 ? W - 1 : xi);
            const int yc = yi < 0 ? 0 : (yi > H - 1 ? H - 1 : yi);
            const uint ro = (rowb + (uint)(yc * W + xc)) * 512u;   // byte row offset
            s_ow[qloc][h][i * 4 + c] = make_uint2(ro, __float_as_uint(wgt));
        }
    }
    __syncthreads();

    // ---- phase 2: thread = (query, head, d4): 8 channels via dwordx4 ----
    const int q = t >> 5, h2 = (t >> 2) & 7, d4 = t & 3;
    int bq = bq0 + q; if (bq > BL_C - 1) bq = BL_C - 1;
    const char* vb = (const char*)value;
    const uint toff = (uint)(h2 * 64 + d4 * 16);

    float a0 = 0.f, a1 = 0.f, a2 = 0.f, a3 = 0.f;
    float a4 = 0.f, a5 = 0.f, a6 = 0.f, a7 = 0.f;
    #pragma unroll 8
    for (int j = 0; j < 64; ++j) {
        const uint2 ow = s_ow[q][h2][j];
        const uint4 v = *(const uint4*)(vb + (size_t)(ow.x + toff));
        const float w = __uint_as_float(ow.y);
        a0 += w * __uint_as_float(v.x << 16);
        a1 += w * __uint_as_float(v.x & 0xffff0000u);
        a2 += w * __uint_as_float(v.y << 16);
        a3 += w * __uint_as_float(v.y & 0xffff0000u);
        a4 += w * __uint_as_float(v.z << 16);
        a5 += w * __uint_as_float(v.z & 0xffff0000u);
        a6 += w * __uint_as_float(v.w << 16);
        a7 += w * __uint_as_float(v.w & 0xffff0000u);
    }
    uint4 o;
    o.x = pkbf(a0, a1); o.y = pkbf(a2, a3);
    o.z = pkbf(a4, a5); o.w = pkbf(a6, a7);
    *(uint4*)(outbf + (size_t)bq * 256 + h2 * 32 + d4 * 8) = o;
}

extern "C" void kernel_launch(void* const* d_in, const int* in_sizes, int n_in,
                              void* d_out, int out_size, void* d_ws, size_t ws_size,
                              hipStream_t stream) {
    const float* src    = (const float*)d_in[0];
    const float* pos    = (const float*)d_in[1];
    const float* refpts = (const float*)d_in[2];
    const float* W_off  = (const float*)d_in[5];
    const float* b_off  = (const float*)d_in[6];
    const float* W_attn = (const float*)d_in[7];
    const float* b_attn = (const float*)d_in[8];
    const float* W_val  = (const float*)d_in[9];
    const float* b_val  = (const float*)d_in[10];
    const float* W_out  = (const float*)d_in[11];
    const float* b_out  = (const float*)d_in[12];
    const float* W1     = (const float*)d_in[13];
    const float* b1     = (const float*)d_in[14];
    const float* W2     = (const float*)d_in[15];
    const float* b2     = (const float*)d_in[16];
    const float* g1     = (const float*)d_in[17];
    const float* be1    = (const float*)d_in[18];
    const float* g2     = (const float*)d_in[19];
    const float* be2    = (const float*)d_in[20];
    float* out = (float*)d_out;
    (void)in_sizes; (void)n_in; (void)out_size; (void)ws_size;

    const int BL = BL_C;
    char* ws = (char*)d_ws;
    const size_t HB  = (size_t)BL * 256 * 2;     // 20.68 MB
    const size_t OAB = (size_t)BL * 384 * 2;     // 31.02 MB

    ushort* q_bf   = (ushort*)(ws);                  // [0, HB)
    ushort* val_bf = (ushort*)(ws + HB);             // [HB, 2HB)
    ushort* oa_bf  = (ushort*)(ws + 2 * HB);         // [2HB, 2HB+OAB)
    ushort* ao_bf  = (ushort*)(ws + 2 * HB + OAB);   // [.., +HB)
    ushort* x_bf   = (ushort*)(ws + 3 * HB + OAB);   // survives to G5
    ushort* mid_bf = (ushort*)(ws);                  // overlays q/val/oa/ao (dead at G4)
    char*   wts    = ws + 4 * HB + OAB;
    ushort* Tval = (ushort*)(wts);               // 256x256
    ushort* Toa  = Tval + 256 * 256;             // 384x256
    ushort* Tout = Toa + 384 * 256;              // 256x256
    ushort* TW1  = Tout + 256 * 256;             // 1024x256
    ushort* TW2  = TW1 + 1024 * 256;             // 256x1024
    float*  boa  = (float*)(TW2 + 256 * 1024);   // 384

    dim3 blk(256);
    const int MT = (BL + 255) / 256;   // 158
    const int MT2 = (BL + 63) / 64;    // 632

    // 1) all prep (weights + q) in one launch
    prep_all<<<dim3(738 + 1024), blk, 0, stream>>>(
        src, pos, W_val, W_off, W_attn, W_out, W1, W2, b_off, b_attn,
        Tval, Toa, Tout, TW1, TW2, boa, q_bf);

    // 2) G1: value = src @ Wv + bv
    gemm_bs<true, false><<<dim3(MT * 4), blk, 0, stream>>>(
        src, Tval, b_val, val_bf, BL, 256, 256, 256, 4, MT * 4);
    // 3) G2: [off|attn] = q @ [Wo|Wa] + [bo|ba]
    gemm_bs<false, false><<<dim3(MT * 6), blk, 0, stream>>>(
        q_bf, Toa, boa, oa_bf, BL, 384, 256, 256, 6, MT * 6);

    // 4) sampling -> ao
    sample_kernel<<<dim3((BL + 7) / 8), blk, 0, stream>>>(val_bf, oa_bf, refpts, ao_bf);

    // 5) G3 + LN1: x = LN(src + ao @ Wout + b_out)
    gemm_ln<256, true, false><<<dim3(MT2), blk, 0, stream>>>(
        ao_bf, Tout, b_out, src, g1, be1, x_bf, MT2);

    // 6) G4: mid = relu(x @ W1 + b1)   (mid overlays q/val/oa/ao)
    gemm_bs<false, true><<<dim3(MT * 16), blk, 0, stream>>>(
        x_bf, TW1, b1, mid_bf, BL, 1024, 256, 256, 16, MT * 16);

    // 7) G5 + LN2: out = LN(x + mid @ W2 + b2) -> f32
    gemm_ln<1024, false, true><<<dim3(MT2), blk, 0, stream>>>(
        mid_bf, TW2, b2, x_bf, g2, be2, out, MT2);
}

// Round 8
// 303.727 us; speedup vs baseline: 1.6719x; 1.0334x over previous
//
#include <hip/hip_runtime.h>
#include <math.h>

#define LEN_IN_C 20197
#define BATCH_C 2
#define BL_C (BATCH_C * LEN_IN_C)   // 40394

typedef short  bf16x8 __attribute__((ext_vector_type(8)));
typedef float  f32x4  __attribute__((ext_vector_type(4)));

__device__ __forceinline__ ushort f2bf(float f) {
    unsigned u = __float_as_uint(f);
    return (ushort)((u + 0x7fffu + ((u >> 16) & 1u)) >> 16);
}
__device__ __forceinline__ float bf2f(ushort u) {
    return __uint_as_float((uint)u << 16);
}
__device__ __forceinline__ uint pkbf(float a, float b) {
    uint r;
    asm("v_cvt_pk_bf16_f32 %0, %1, %2" : "=v"(r) : "v"(a), "v"(b));
    return r;
}
__device__ __forceinline__ void gload16(const void* g, void* l) {
    __builtin_amdgcn_global_load_lds(
        (const __attribute__((address_space(1))) unsigned char*)g,
        (__attribute__((address_space(3))) unsigned char*)l, 16, 0, 0);
}
__device__ __forceinline__ int xcd_swz(int lid, int nwg) {
    const int q = nwg >> 3, r = nwg & 7;
    const int xcd = lid & 7, p = lid >> 3;
    return (xcd < r ? xcd * (q + 1) : r * (q + 1) + (xcd - r) * q) + p;
}

// ================= combined prep kernel (weights + q + src_bf) =================
__device__ __forceinline__ void tcast32(
    const float* W, ushort* WT, int K, int N, int n0, int k0, float* tile /*32*33*/)
{
    const int ty = threadIdx.x >> 3, tx = threadIdx.x & 7;
    float4 v = *(const float4*)(W + (size_t)(k0 + ty) * N + n0 + tx * 4);
    tile[ty * 33 + tx * 4 + 0] = v.x; tile[ty * 33 + tx * 4 + 1] = v.y;
    tile[ty * 33 + tx * 4 + 2] = v.z; tile[ty * 33 + tx * 4 + 3] = v.w;
    __syncthreads();
    ushort4 o;
    o.x = f2bf(tile[(tx * 4 + 0) * 33 + ty]);
    o.y = f2bf(tile[(tx * 4 + 1) * 33 + ty]);
    o.z = f2bf(tile[(tx * 4 + 2) * 33 + ty]);
    o.w = f2bf(tile[(tx * 4 + 3) * 33 + ty]);
    *(ushort4*)(WT + (size_t)(n0 + ty) * K + k0 + tx * 4) = o;
}

__global__ __launch_bounds__(256) void prep_all(
    const float* __restrict__ src, const float* __restrict__ pos,
    const float* __restrict__ Wv, const float* __restrict__ Wo,
    const float* __restrict__ Wa, const float* __restrict__ Wout,
    const float* __restrict__ W1, const float* __restrict__ W2,
    const float* __restrict__ bo, const float* __restrict__ ba,
    ushort* __restrict__ Tval, ushort* __restrict__ Toa,
    ushort* __restrict__ Tout, ushort* __restrict__ TW1,
    ushort* __restrict__ TW2, float* __restrict__ boa,
    ushort* __restrict__ qout, ushort* __restrict__ srcb)
{
    __shared__ float tile[32 * 33];
    const int bx = blockIdx.x;
    const int tid = threadIdx.x;
    if (bx < 64) {                       // Tval: 256x256
        tcast32(Wv, Tval, 256, 256, (bx & 7) * 32, (bx >> 3) * 32, tile);
    } else if (bx < 128) {               // Tout
        const int s = bx - 64;
        tcast32(Wout, Tout, 256, 256, (s & 7) * 32, (s >> 3) * 32, tile);
    } else if (bx < 384) {               // TW1: K=256 N=1024
        const int s = bx - 128;
        tcast32(W1, TW1, 256, 1024, (s & 31) * 32, (s >> 5) * 32, tile);
    } else if (bx < 640) {               // TW2: K=1024 N=256
        const int s = bx - 384;
        tcast32(W2, TW2, 1024, 256, (s & 7) * 32, (s >> 3) * 32, tile);
    } else if (bx < 736) {               // Toa: 384x64 ushort4 tasks
        const int idx = (bx - 640) * 256 + tid;
        const int n = idx >> 6, k4 = (idx & 63) * 4;
        ushort4 o; ushort* po = (ushort*)&o;
        #pragma unroll
        for (int j = 0; j < 4; ++j) {
            const int k = k4 + j;
            const float v = (n < 256) ? Wo[(size_t)k * 256 + n]
                                      : Wa[(size_t)k * 128 + (n - 256)];
            po[j] = f2bf(v);
        }
        *(ushort4*)(Toa + (size_t)n * 256 + k4) = o;
    } else if (bx < 738) {               // boa
        const int n = (bx - 736) * 256 + tid;
        if (n < 384) boa[n] = (n < 256) ? bo[n] : ba[n - 256];
    } else {                             // stream: q = bf(src+pos), srcb = bf(src)
        const int n8 = BL_C * 32;
        for (int i = (bx - 738) * 256 + tid; i < n8; i += 1024 * 256) {
            const size_t base = (size_t)i * 8;
            float4 a0 = *(const float4*)(src + base);
            float4 a1 = *(const float4*)(src + base + 4);
            float4 b0 = *(const float4*)(pos + base);
            float4 b1 = *(const float4*)(pos + base + 4);
            uint4 o;
            o.x = pkbf(a0.x + b0.x, a0.y + b0.y);
            o.y = pkbf(a0.z + b0.z, a0.w + b0.w);
            o.z = pkbf(a1.x + b1.x, a1.y + b1.y);
            o.w = pkbf(a1.z + b1.z, a1.w + b1.w);
            *(uint4*)(qout + base) = o;
            uint4 s4;
            s4.x = pkbf(a0.x, a0.y); s4.y = pkbf(a0.z, a0.w);
            s4.z = pkbf(a1.x, a1.y); s4.w = pkbf(a1.z, a1.w);
            *(uint4*)(srcb + base) = s4;
        }
    }
}

// ================= B-stationary MFMA GEMM, full-chunk A prefetch =================
// C(bf16, M x N) = A @ BT^T + bias.  Block = 128 rows x 64 cols, 4 waves
// stacked in M (wave = 32 rows x 64 cols). Per KC=256 chunk: issue ALL A-loads
// (8 slots x 2 frags), then stage B into LDS, then __syncthreads (drains
// vmcnt(0) -> A lands in regs for free), then a pure regs+LDS K-loop.
template <bool RELU>
__global__ __launch_bounds__(256) void gemm_bs(
    const ushort* __restrict__ A, const ushort* __restrict__ BT,
    const float* __restrict__ bias, ushort* __restrict__ C,
    const int M, const int N, const int K, const int NT, const int nwg)
{
    __shared__ ushort lsB[64 * 256];   // 32KB

    const int nid = xcd_swz(blockIdx.x, nwg);
    const int nt = nid % NT, mt = nid / NT;
    const int row0 = mt * 128, col0 = nt * 64;

    const int tid = threadIdx.x;
    const int ln = tid & 63, wv = tid >> 6;
    const int l16 = ln & 15, lk = ln >> 4;

    uint abase[2];
    #pragma unroll
    for (int m = 0; m < 2; ++m) {
        int rr = row0 + wv * 32 + m * 16 + l16;
        if (rr > M - 1) rr = M - 1;
        abase[m] = (uint)rr * K + lk * 8;
    }
    uint bbase[4], bxor[4];
    #pragma unroll
    for (int n = 0; n < 4; ++n) {
        const int brow = n * 16 + l16;
        bbase[n] = (uint)(brow * 512 + lk * 16);
        bxor[n]  = (uint)((brow & 7) << 4);
    }

    f32x4 acc[2][4] = {};
    const int nch = K >> 8;

    for (int ch = 0; ch < nch; ++ch) {
        const int kc0 = ch << 8;

        // ---- full-chunk A prefetch: 16 loads, no LDS dependence ----
        bf16x8 ar[8][2];
        #pragma unroll
        for (int s = 0; s < 8; ++s)
            #pragma unroll
            for (int m = 0; m < 2; ++m)
                ar[s][m] = *(const bf16x8*)(A + abase[m] + kc0 + s * 32);

        if (ch) __syncthreads();
        // ---- stage B chunk (64 N-rows x 256 K): linear dest, inv-swizzled src ----
        #pragma unroll
        for (int j = 0; j < 8; ++j) {
            const int d = j * 256 + tid;
            const int brow = d >> 5;
            const int c = (d & 31) ^ (brow & 7);
            gload16(BT + (size_t)(col0 + brow) * K + kc0 + c * 8,
                    (char*)lsB + j * 4096 + wv * 1024);
        }
        __syncthreads();   // drains vmcnt(0): B in LDS AND A in regs

        // ---- pure regs+LDS K-loop: 8 steps of K=32 ----
        #pragma unroll
        for (int gs = 0; gs < 8; ++gs) {
            bf16x8 bv[4];
            #pragma unroll
            for (int n = 0; n < 4; ++n)
                bv[n] = *(const bf16x8*)((const char*)lsB +
                        ((bbase[n] + gs * 64) ^ bxor[n]));
            #pragma unroll
            for (int m = 0; m < 2; ++m)
                #pragma unroll
                for (int n = 0; n < 4; ++n)
                    acc[m][n] = __builtin_amdgcn_mfma_f32_16x16x32_bf16(
                        bv[n], ar[gs][m], acc[m][n], 0, 0, 0);
        }
    }

    // ---- epilogue: lane owns 4 consecutive cols of one row per (m,n) ----
    #pragma unroll
    for (int m = 0; m < 2; ++m) {
        const int grow = row0 + wv * 32 + m * 16 + l16;
        if (grow >= M) continue;
        ushort* crow = C + (size_t)grow * N;
        #pragma unroll
        for (int n = 0; n < 4; ++n) {
            const int col4 = col0 + n * 16 + lk * 4;
            float4 bs = *(const float4*)(bias + col4);
            f32x4 v = acc[m][n];
            float o0 = v[0] + bs.x, o1 = v[1] + bs.y, o2 = v[2] + bs.z, o3 = v[3] + bs.w;
            if (RELU) {
                o0 = fmaxf(o0, 0.f); o1 = fmaxf(o1, 0.f);
                o2 = fmaxf(o2, 0.f); o3 = fmaxf(o3, 0.f);
            }
            *(uint2*)(crow + col4) = make_uint2(pkbf(o0, o1), pkbf(o2, o3));
        }
    }
}

// ================= MS-deformable sampling: 1 block = 8 queries =================
__global__ __launch_bounds__(256) void sample_kernel(
    const ushort* __restrict__ value,    // (B, L, 256) bf16
    const ushort* __restrict__ oa,       // (BL, 384) bf16: [off 256 | attn 128]
    const float* __restrict__ ref,       // (BL, 8)
    ushort* __restrict__ outbf)          // (BL, 256) bf16
{
    constexpr int Hs[4] = {100, 50, 25, 13};
    constexpr int Ws[4] = {152, 76, 38, 19};
    constexpr int St[4] = {0, 15200, 19000, 19950};
    constexpr int NWG = (BL_C + 7) / 8;    // 5050

    const int bq0 = xcd_swz(blockIdx.x, NWG) * 8;
    const int t = threadIdx.x;

    __shared__ uint2 s_ow[8][8][65];

    // ---- phase 1: 4 rounds x 2 queries ----
    #pragma unroll
    for (int rnd = 0; rnd < 4; ++rnd) {
        const int qi2 = t >> 7, r2 = t & 127;
        const int qloc = rnd * 2 + qi2;
        int bq = bq0 + qloc; if (bq > BL_C - 1) bq = BL_C - 1;
        const int b = (bq >= LEN_IN_C) ? 1 : 0;
        const int h = r2 >> 4, i = r2 & 15, l = i >> 2, p = i & 3;
        const ushort* crow = oa + (size_t)bq * 384;

        float lg = bf2f(crow[256 + h * 16 + i]);
        float mx = lg;
        #pragma unroll
        for (int o = 1; o < 16; o <<= 1) mx = fmaxf(mx, __shfl_xor(mx, o, 16));
        float e = __expf(lg - mx), sm = e;
        #pragma unroll
        for (int o = 1; o < 16; o <<= 1) sm += __shfl_xor(sm, o, 16);
        const float aw = e / sm;

        const uint ov = *(const uint*)(crow + h * 32 + l * 8 + p * 2);
        const float ox = __uint_as_float(ov << 16);
        const float oy = __uint_as_float(ov & 0xffff0000u);
        const float2 rxy = *(const float2*)(ref + (size_t)bq * 8 + l * 2);
        const int H = Hs[l], W = Ws[l];
        const float x = rxy.x * (float)W + ox - 0.5f;
        const float y = rxy.y * (float)H + oy - 0.5f;
        const float x0f = floorf(x), y0f = floorf(y);
        const float fx = x - x0f, fy = y - y0f;
        const int x0 = (int)x0f, y0 = (int)y0f;
        const uint rowb = (uint)(b * LEN_IN_C + St[l]);
        #pragma unroll
        for (int c = 0; c < 4; ++c) {
            const int dx = c & 1, dy = c >> 1;
            const int xi = x0 + dx, yi = y0 + dy;
            const bool valid = (xi >= 0) & (xi < W) & (yi >= 0) & (yi < H);
            float wgt = (dx ? fx : 1.f - fx) * (dy ? fy : 1.f - fy) * aw;
            if (!valid) wgt = 0.f;
            const int xc = xi < 0 ? 0 : (xi > W - 1 ? W - 1 : xi);
            const int yc = yi < 0 ? 0 : (yi > H - 1 ? H - 1 : yi);
            const uint ro = (rowb + (uint)(yc * W + xc)) * 512u;   // byte row offset
            s_ow[qloc][h][i * 4 + c] = make_uint2(ro, __float_as_uint(wgt));
        }
    }
    __syncthreads();

    // ---- phase 2: thread = (query, head, d4): 8 channels via dwordx4 ----
    const int q = t >> 5, h2 = (t >> 2) & 7, d4 = t & 3;
    int bq = bq0 + q; if (bq > BL_C - 1) bq = BL_C - 1;
    const char* vb = (const char*)value;
    const uint toff = (uint)(h2 * 64 + d4 * 16);

    float a0 = 0.f, a1 = 0.f, a2 = 0.f, a3 = 0.f;
    float a4 = 0.f, a5 = 0.f, a6 = 0.f, a7 = 0.f;
    #pragma unroll 8
    for (int j = 0; j < 64; ++j) {
        const uint2 ow = s_ow[q][h2][j];
        const uint4 v = *(const uint4*)(vb + (size_t)(ow.x + toff));
        const float w = __uint_as_float(ow.y);
        a0 += w * __uint_as_float(v.x << 16);
        a1 += w * __uint_as_float(v.x & 0xffff0000u);
        a2 += w * __uint_as_float(v.y << 16);
        a3 += w * __uint_as_float(v.y & 0xffff0000u);
        a4 += w * __uint_as_float(v.z << 16);
        a5 += w * __uint_as_float(v.z & 0xffff0000u);
        a6 += w * __uint_as_float(v.w << 16);
        a7 += w * __uint_as_float(v.w & 0xffff0000u);
    }
    uint4 o;
    o.x = pkbf(a0, a1); o.y = pkbf(a2, a3);
    o.z = pkbf(a4, a5); o.w = pkbf(a6, a7);
    *(uint4*)(outbf + (size_t)bq * 256 + h2 * 32 + d4 * 8) = o;
}

// ================ fused residual-add + LayerNorm: wave per row ================
template <bool ABF, bool OF32>
__global__ __launch_bounds__(256) void add_ln(
    const void* __restrict__ ap, const ushort* __restrict__ bp,
    const float* __restrict__ g, const float* __restrict__ be,
    void* __restrict__ op)
{
    const int row = blockIdx.x * 4 + (threadIdx.x >> 6);
    if (row >= BL_C) return;
    const int ln = threadIdx.x & 63;
    const size_t base = (size_t)row * 256 + ln * 4;

    float x[4];
    if (ABF) {
        ushort4 a4 = *(const ushort4*)((const ushort*)ap + base);
        x[0] = bf2f(a4.x); x[1] = bf2f(a4.y); x[2] = bf2f(a4.z); x[3] = bf2f(a4.w);
    } else {
        float4 a4 = *(const float4*)((const float*)ap + base);
        x[0] = a4.x; x[1] = a4.y; x[2] = a4.z; x[3] = a4.w;
    }
    ushort4 b4 = *(const ushort4*)(bp + base);
    x[0] += bf2f(b4.x); x[1] += bf2f(b4.y); x[2] += bf2f(b4.z); x[3] += bf2f(b4.w);

    float s = x[0] + x[1] + x[2] + x[3];
    #pragma unroll
    for (int o = 32; o >= 1; o >>= 1) s += __shfl_xor(s, o, 64);
    const float mean = s * (1.f / 256.f);
    float d0 = x[0] - mean, d1 = x[1] - mean, d2 = x[2] - mean, d3 = x[3] - mean;
    float ss = d0 * d0 + d1 * d1 + d2 * d2 + d3 * d3;
    #pragma unroll
    for (int o = 32; o >= 1; o >>= 1) ss += __shfl_xor(ss, o, 64);
    const float rs = rsqrtf(ss * (1.f / 256.f) + 1e-5f);

    float4 gv = *(const float4*)(g + ln * 4);
    float4 bv = *(const float4*)(be + ln * 4);
    float o0 = d0 * rs * gv.x + bv.x;
    float o1 = d1 * rs * gv.y + bv.y;
    float o2 = d2 * rs * gv.z + bv.z;
    float o3 = d3 * rs * gv.w + bv.w;

    if (OF32) {
        *(float4*)((float*)op + base) = make_float4(o0, o1, o2, o3);
    } else {
        ushort4 st;
        st.x = f2bf(o0); st.y = f2bf(o1); st.z = f2bf(o2); st.w = f2bf(o3);
        *(ushort4*)((ushort*)op + base) = st;
    }
}

extern "C" void kernel_launch(void* const* d_in, const int* in_sizes, int n_in,
                              void* d_out, int out_size, void* d_ws, size_t ws_size,
                              hipStream_t stream) {
    const float* src    = (const float*)d_in[0];
    const float* pos    = (const float*)d_in[1];
    const float* refpts = (const float*)d_in[2];
    const float* W_off  = (const float*)d_in[5];
    const float* b_off  = (const float*)d_in[6];
    const float* W_attn = (const float*)d_in[7];
    const float* b_attn = (const float*)d_in[8];
    const float* W_val  = (const float*)d_in[9];
    const float* b_val  = (const float*)d_in[10];
    const float* W_out  = (const float*)d_in[11];
    const float* b_out  = (const float*)d_in[12];
    const float* W1     = (const float*)d_in[13];
    const float* b1     = (const float*)d_in[14];
    const float* W2     = (const float*)d_in[15];
    const float* b2     = (const float*)d_in[16];
    const float* g1     = (const float*)d_in[17];
    const float* be1    = (const float*)d_in[18];
    const float* g2     = (const float*)d_in[19];
    const float* be2    = (const float*)d_in[20];
    float* out = (float*)d_out;
    (void)in_sizes; (void)n_in; (void)out_size; (void)ws_size;

    const int BL = BL_C;
    char* ws = (char*)d_ws;
    const size_t HB  = (size_t)BL * 256 * 2;     // 20.68 MB
    const size_t OAB = (size_t)BL * 384 * 2;     // 31.02 MB

    // regions: A:[q -> x] B:[val] C:[oa] D:[ao] D2:[src2] E:[src_bf -> ffn2]
    ushort* q_bf    = (ushort*)(ws);                       // A
    ushort* x_bf    = (ushort*)(ws);                       // A (q dead after G2)
    ushort* val_bf  = (ushort*)(ws + HB);                  // B
    ushort* oa_bf   = (ushort*)(ws + 2 * HB);              // C
    ushort* ao_bf   = (ushort*)(ws + 2 * HB + OAB);        // D
    ushort* src2_bf = (ushort*)(ws + 3 * HB + OAB);        // D2
    ushort* srcb_bf = (ushort*)(ws + 4 * HB + OAB);        // E
    ushort* ffn2_bf = srcb_bf;                             // E (src_bf dead after G1)
    ushort* mid_bf  = val_bf;                              // overlays B,C,D,D2 (93 MB)
    char*   wts     = ws + 5 * HB + OAB;
    ushort* Tval = (ushort*)(wts);               // 256x256
    ushort* Toa  = Tval + 256 * 256;             // 384x256
    ushort* Tout = Toa + 384 * 256;              // 256x256
    ushort* TW1  = Tout + 256 * 256;             // 1024x256
    ushort* TW2  = TW1 + 1024 * 256;             // 256x1024
    float*  boa  = (float*)(TW2 + 256 * 1024);   // 384

    dim3 blk(256);
    const int MT = (BL + 127) / 128;   // 316

    // 1) all prep (weights + q + src_bf)
    prep_all<<<dim3(738 + 1024), blk, 0, stream>>>(
        src, pos, W_val, W_off, W_attn, W_out, W1, W2, b_off, b_attn,
        Tval, Toa, Tout, TW1, TW2, boa, q_bf, srcb_bf);

    // 2) G1: value = src @ Wv + bv
    gemm_bs<false><<<dim3(MT * 4), blk, 0, stream>>>(
        srcb_bf, Tval, b_val, val_bf, BL, 256, 256, 4, MT * 4);
    // 3) G2: [off|attn] = q @ [Wo|Wa] + [bo|ba]
    gemm_bs<false><<<dim3(MT * 6), blk, 0, stream>>>(
        q_bf, Toa, boa, oa_bf, BL, 384, 256, 6, MT * 6);

    // 4) sampling -> ao
    sample_kernel<<<dim3((BL + 7) / 8), blk, 0, stream>>>(val_bf, oa_bf, refpts, ao_bf);

    // 5) G3: src2 = ao @ Wout + b_out
    gemm_bs<false><<<dim3(MT * 4), blk, 0, stream>>>(
        ao_bf, Tout, b_out, src2_bf, BL, 256, 256, 4, MT * 4);

    // 6) LN1: x = LN(src + src2)   (f32 src residual protects accuracy)
    add_ln<false, false><<<dim3((BL + 3) / 4), blk, 0, stream>>>(
        src, src2_bf, g1, be1, x_bf);

    // 7) G4: mid = relu(x @ W1 + b1)   (mid overlays val/oa/ao/src2)
    gemm_bs<true><<<dim3(MT * 16), blk, 0, stream>>>(
        x_bf, TW1, b1, mid_bf, BL, 1024, 256, 16, MT * 16);

    // 8) G5: ffn2 = mid @ W2 + b2   (overlays src_bf)
    gemm_bs<false><<<dim3(MT * 4), blk, 0, stream>>>(
        mid_bf, TW2, b2, ffn2_bf, BL, 256, 1024, 4, MT * 4);

    // 9) LN2: out = LN(x + ffn2) -> f32
    add_ln<true, true><<<dim3((BL + 3) / 4), blk, 0, stream>>>(
        x_bf, ffn2_bf, g2, be2, out);
}

// Round 10
// 298.315 us; speedup vs baseline: 1.7022x; 1.0181x over previous
//
#include <hip/hip_runtime.h>
#include <hip/hip_fp16.h>
#include <math.h>

#define LEN_IN_C 20197
#define BATCH_C 2
#define BL_C (BATCH_C * LEN_IN_C)   // 40394

typedef short  bf16x8 __attribute__((ext_vector_type(8)));
typedef float  f32x4  __attribute__((ext_vector_type(4)));

__device__ __forceinline__ ushort f2bf(float f) {
    unsigned u = __float_as_uint(f);
    return (ushort)((u + 0x7fffu + ((u >> 16) & 1u)) >> 16);
}
__device__ __forceinline__ float bf2f(ushort u) {
    return __uint_as_float((uint)u << 16);
}
__device__ __forceinline__ uint pkbf(float a, float b) {
    uint r;
    asm("v_cvt_pk_bf16_f32 %0, %1, %2" : "=v"(r) : "v"(a), "v"(b));
    return r;
}
__device__ __forceinline__ uint pkhalf(float a, float b) {
    const ushort ha = __half_as_ushort(__float2half_rn(a));
    const ushort hb = __half_as_ushort(__float2half_rn(b));
    return (uint)ha | ((uint)hb << 16);
}
__device__ __forceinline__ float h2f_lo(uint u) {
    return __half2float(__ushort_as_half((ushort)(u & 0xffffu)));
}
__device__ __forceinline__ float h2f_hi(uint u) {
    return __half2float(__ushort_as_half((ushort)(u >> 16)));
}
__device__ __forceinline__ void gload16(const void* g, void* l) {
    __builtin_amdgcn_global_load_lds(
        (const __attribute__((address_space(1))) unsigned char*)g,
        (__attribute__((address_space(3))) unsigned char*)l, 16, 0, 0);
}
__device__ __forceinline__ int xcd_swz(int lid, int nwg) {
    const int q = nwg >> 3, r = nwg & 7;
    const int xcd = lid & 7, p = lid >> 3;
    return (xcd < r ? xcd * (q + 1) : r * (q + 1) + (xcd - r) * q) + p;
}

// ================= combined prep kernel (weights + q + src_bf) =================
__device__ __forceinline__ void tcast32(
    const float* W, ushort* WT, int K, int N, int n0, int k0, float* tile /*32*33*/)
{
    const int ty = threadIdx.x >> 3, tx = threadIdx.x & 7;
    float4 v = *(const float4*)(W + (size_t)(k0 + ty) * N + n0 + tx * 4);
    tile[ty * 33 + tx * 4 + 0] = v.x; tile[ty * 33 + tx * 4 + 1] = v.y;
    tile[ty * 33 + tx * 4 + 2] = v.z; tile[ty * 33 + tx * 4 + 3] = v.w;
    __syncthreads();
    ushort4 o;
    o.x = f2bf(tile[(tx * 4 + 0) * 33 + ty]);
    o.y = f2bf(tile[(tx * 4 + 1) * 33 + ty]);
    o.z = f2bf(tile[(tx * 4 + 2) * 33 + ty]);
    o.w = f2bf(tile[(tx * 4 + 3) * 33 + ty]);
    *(ushort4*)(WT + (size_t)(n0 + ty) * K + k0 + tx * 4) = o;
}

__global__ __launch_bounds__(256) void prep_all(
    const float* __restrict__ src, const float* __restrict__ pos,
    const float* __restrict__ Wv, const float* __restrict__ Wo,
    const float* __restrict__ Wa, const float* __restrict__ Wout,
    const float* __restrict__ W1, const float* __restrict__ W2,
    const float* __restrict__ bo, const float* __restrict__ ba,
    ushort* __restrict__ Tval, ushort* __restrict__ Toa,
    ushort* __restrict__ Tout, ushort* __restrict__ TW1,
    ushort* __restrict__ TW2, float* __restrict__ boa,
    ushort* __restrict__ qout, ushort* __restrict__ srcb)
{
    __shared__ float tile[32 * 33];
    const int bx = blockIdx.x;
    const int tid = threadIdx.x;
    if (bx < 64) {
        tcast32(Wv, Tval, 256, 256, (bx & 7) * 32, (bx >> 3) * 32, tile);
    } else if (bx < 128) {
        const int s = bx - 64;
        tcast32(Wout, Tout, 256, 256, (s & 7) * 32, (s >> 3) * 32, tile);
    } else if (bx < 384) {
        const int s = bx - 128;
        tcast32(W1, TW1, 256, 1024, (s & 31) * 32, (s >> 5) * 32, tile);
    } else if (bx < 640) {
        const int s = bx - 384;
        tcast32(W2, TW2, 1024, 256, (s & 7) * 32, (s >> 3) * 32, tile);
    } else if (bx < 736) {
        const int idx = (bx - 640) * 256 + tid;
        const int n = idx >> 6, k4 = (idx & 63) * 4;
        ushort4 o; ushort* po = (ushort*)&o;
        #pragma unroll
        for (int j = 0; j < 4; ++j) {
            const int k = k4 + j;
            const float v = (n < 256) ? Wo[(size_t)k * 256 + n]
                                      : Wa[(size_t)k * 128 + (n - 256)];
            po[j] = f2bf(v);
        }
        *(ushort4*)(Toa + (size_t)n * 256 + k4) = o;
    } else if (bx < 738) {
        const int n = (bx - 736) * 256 + tid;
        if (n < 384) boa[n] = (n < 256) ? bo[n] : ba[n - 256];
    } else {
        const int n8 = BL_C * 32;
        for (int i = (bx - 738) * 256 + tid; i < n8; i += 1024 * 256) {
            const size_t base = (size_t)i * 8;
            float4 a0 = *(const float4*)(src + base);
            float4 a1 = *(const float4*)(src + base + 4);
            float4 b0 = *(const float4*)(pos + base);
            float4 b1 = *(const float4*)(pos + base + 4);
            uint4 o;
            o.x = pkbf(a0.x + b0.x, a0.y + b0.y);
            o.y = pkbf(a0.z + b0.z, a0.w + b0.w);
            o.z = pkbf(a1.x + b1.x, a1.y + b1.y);
            o.w = pkbf(a1.z + b1.z, a1.w + b1.w);
            *(uint4*)(qout + base) = o;
            uint4 s4;
            s4.x = pkbf(a0.x, a0.y); s4.y = pkbf(a0.z, a0.w);
            s4.z = pkbf(a1.x, a1.y); s4.w = pkbf(a1.z, a1.w);
            *(uint4*)(srcb + base) = s4;
        }
    }
}

// ================= B-stationary MFMA GEMM, full-chunk A prefetch =================
template <bool RELU>
__global__ __launch_bounds__(256) void gemm_bs(
    const ushort* __restrict__ A, const ushort* __restrict__ BT,
    const float* __restrict__ bias, ushort* __restrict__ C,
    const int M, const int N, const int K, const int NT, const int nwg)
{
    __shared__ ushort lsB[64 * 256];   // 32KB

    const int nid = xcd_swz(blockIdx.x, nwg);
    const int nt = nid % NT, mt = nid / NT;
    const int row0 = mt * 128, col0 = nt * 64;

    const int tid = threadIdx.x;
    const int ln = tid & 63, wv = tid >> 6;
    const int l16 = ln & 15, lk = ln >> 4;

    uint abase[2];
    #pragma unroll
    for (int m = 0; m < 2; ++m) {
        int rr = row0 + wv * 32 + m * 16 + l16;
        if (rr > M - 1) rr = M - 1;
        abase[m] = (uint)rr * K + lk * 8;
    }
    uint bbase[4], bxor[4];
    #pragma unroll
    for (int n = 0; n < 4; ++n) {
        const int brow = n * 16 + l16;
        bbase[n] = (uint)(brow * 512 + lk * 16);
        bxor[n]  = (uint)((brow & 7) << 4);
    }

    f32x4 acc[2][4] = {};
    const int nch = K >> 8;

    for (int ch = 0; ch < nch; ++ch) {
        const int kc0 = ch << 8;

        bf16x8 ar[8][2];
        #pragma unroll
        for (int s = 0; s < 8; ++s)
            #pragma unroll
            for (int m = 0; m < 2; ++m)
                ar[s][m] = *(const bf16x8*)(A + abase[m] + kc0 + s * 32);

        if (ch) __syncthreads();
        #pragma unroll
        for (int j = 0; j < 8; ++j) {
            const int d = j * 256 + tid;
            const int brow = d >> 5;
            const int c = (d & 31) ^ (brow & 7);
            gload16(BT + (size_t)(col0 + brow) * K + kc0 + c * 8,
                    (char*)lsB + j * 4096 + wv * 1024);
        }
        __syncthreads();   // drains vmcnt(0): B in LDS AND A in regs

        #pragma unroll
        for (int gs = 0; gs < 8; ++gs) {
            bf16x8 bv[4];
            #pragma unroll
            for (int n = 0; n < 4; ++n)
                bv[n] = *(const bf16x8*)((const char*)lsB +
                        ((bbase[n] + gs * 64) ^ bxor[n]));
            #pragma unroll
            for (int m = 0; m < 2; ++m)
                #pragma unroll
                for (int n = 0; n < 4; ++n)
                    acc[m][n] = __builtin_amdgcn_mfma_f32_16x16x32_bf16(
                        bv[n], ar[gs][m], acc[m][n], 0, 0, 0);
        }
    }

    #pragma unroll
    for (int m = 0; m < 2; ++m) {
        const int grow = row0 + wv * 32 + m * 16 + l16;
        if (grow >= M) continue;
        ushort* crow = C + (size_t)grow * N;
        #pragma unroll
        for (int n = 0; n < 4; ++n) {
            const int col4 = col0 + n * 16 + lk * 4;
            float4 bs = *(const float4*)(bias + col4);
            f32x4 v = acc[m][n];
            float o0 = v[0] + bs.x, o1 = v[1] + bs.y, o2 = v[2] + bs.z, o3 = v[3] + bs.w;
            if (RELU) {
                o0 = fmaxf(o0, 0.f); o1 = fmaxf(o1, 0.f);
                o2 = fmaxf(o2, 0.f); o3 = fmaxf(o3, 0.f);
            }
            *(uint2*)(crow + col4) = make_uint2(pkbf(o0, o1), pkbf(o2, o3));
        }
    }
}

// ================= MS-deformable sampling: 1 block = 8 queries =================
// Pair-packed: per (h, point, y-row) one entry {byte_off, wL|wR fp16x2} covering
// the two x-adjacent corners (value rows off and off+512). LDS ~16.9 KB ->
// 8 blocks/CU (full wave occupancy).
__global__ __launch_bounds__(256) void sample_kernel(
    const ushort* __restrict__ value,    // (B, L, 256) bf16
    const ushort* __restrict__ oa,       // (BL, 384) bf16: [off 256 | attn 128]
    const float* __restrict__ ref,       // (BL, 8)
    ushort* __restrict__ outbf)          // (BL, 256) bf16
{
    constexpr int Hs[4] = {100, 50, 25, 13};
    constexpr int Ws[4] = {152, 76, 38, 19};
    constexpr int St[4] = {0, 15200, 19000, 19950};
    constexpr int NWG = (BL_C + 7) / 8;    // 5050

    const int bq0 = xcd_swz(blockIdx.x, NWG) * 8;
    const int t = threadIdx.x;

    __shared__ uint2 s_pw[8][8][33];   // [q][h][pair j=i*2+dy], 16.9 KB

    // ---- phase 1: 4 rounds x 2 queries; each lane owns one (h, l, p) ----
    #pragma unroll
    for (int rnd = 0; rnd < 4; ++rnd) {
        const int qi2 = t >> 7, r2 = t & 127;
        const int qloc = rnd * 2 + qi2;
        int bq = bq0 + qloc; if (bq > BL_C - 1) bq = BL_C - 1;
        const int b = (bq >= LEN_IN_C) ? 1 : 0;
        const int h = r2 >> 4, i = r2 & 15, l = i >> 2, p = i & 3;
        const ushort* crow = oa + (size_t)bq * 384;

        float lg = bf2f(crow[256 + h * 16 + i]);
        float mx = lg;
        #pragma unroll
        for (int o = 1; o < 16; o <<= 1) mx = fmaxf(mx, __shfl_xor(mx, o, 16));
        float e = __expf(lg - mx), sm = e;
        #pragma unroll
        for (int o = 1; o < 16; o <<= 1) sm += __shfl_xor(sm, o, 16);
        const float aw = e / sm;

        const uint ov = *(const uint*)(crow + h * 32 + l * 8 + p * 2);
        const float ox = __uint_as_float(ov << 16);
        const float oy = __uint_as_float(ov & 0xffff0000u);
        const float2 rxy = *(const float2*)(ref + (size_t)bq * 8 + l * 2);
        const int H = Hs[l], W = Ws[l];
        const float x = rxy.x * (float)W + ox - 0.5f;
        const float y = rxy.y * (float)H + oy - 0.5f;
        const float x0f = floorf(x), y0f = floorf(y);
        const float fx = x - x0f, fy = y - y0f;
        const int x0 = (int)x0f, y0 = (int)y0f;

        // x-pair: base xb covers positions {xb, xb+1}; remap corner weights
        const float wx0 = (x0 >= 0 && x0 < W) ? (1.f - fx) : 0.f;
        const float wx1 = (x0 + 1 >= 0 && x0 + 1 < W) ? fx : 0.f;
        int xb = x0 < 0 ? 0 : (x0 > W - 2 ? W - 2 : x0);
        float wLx = (xb == x0) ? wx0 : ((xb == x0 + 1) ? wx1 : 0.f);
        float wRx = (xb + 1 == x0 + 1) ? wx1 : ((xb + 1 == x0) ? wx0 : 0.f);
        wLx *= aw; wRx *= aw;

        const uint rowb = (uint)(b * LEN_IN_C + St[l] + xb);
        #pragma unroll
        for (int dy = 0; dy < 2; ++dy) {
            const int yy = y0 + dy;
            const bool vy = (yy >= 0) & (yy < H);
            const float wy = vy ? (dy ? fy : 1.f - fy) : 0.f;
            const int yc = yy < 0 ? 0 : (yy > H - 1 ? H - 1 : yy);
            const uint off = (rowb + (uint)(yc * W)) * 512u;
            s_pw[qloc][h][i * 2 + dy] = make_uint2(off, pkhalf(wLx * wy, wRx * wy));
        }
    }
    __syncthreads();

    // ---- phase 2: thread = (query, head, d4): 8 channels, 32 pair-iters ----
    const int q = t >> 5, h2 = (t >> 2) & 7, d4 = t & 3;
    int bq = bq0 + q; if (bq > BL_C - 1) bq = BL_C - 1;
    const char* vb = (const char*)value;
    const uint toff = (uint)(h2 * 64 + d4 * 16);

    float a0 = 0.f, a1 = 0.f, a2 = 0.f, a3 = 0.f;
    float a4 = 0.f, a5 = 0.f, a6 = 0.f, a7 = 0.f;
    #pragma unroll 4
    for (int j = 0; j < 32; ++j) {
        const uint2 pw = s_pw[q][h2][j];
        const char* p = vb + (size_t)(pw.x + toff);
        const uint4 v0 = *(const uint4*)p;
        const uint4 v1 = *(const uint4*)(p + 512);
        const float wL = h2f_lo(pw.y), wR = h2f_hi(pw.y);
        a0 += wL * __uint_as_float(v0.x << 16);
        a1 += wL * __uint_as_float(v0.x & 0xffff0000u);
        a2 += wL * __uint_as_float(v0.y << 16);
        a3 += wL * __uint_as_float(v0.y & 0xffff0000u);
        a4 += wL * __uint_as_float(v0.z << 16);
        a5 += wL * __uint_as_float(v0.z & 0xffff0000u);
        a6 += wL * __uint_as_float(v0.w << 16);
        a7 += wL * __uint_as_float(v0.w & 0xffff0000u);
        a0 += wR * __uint_as_float(v1.x << 16);
        a1 += wR * __uint_as_float(v1.x & 0xffff0000u);
        a2 += wR * __uint_as_float(v1.y << 16);
        a3 += wR * __uint_as_float(v1.y & 0xffff0000u);
        a4 += wR * __uint_as_float(v1.z << 16);
        a5 += wR * __uint_as_float(v1.z & 0xffff0000u);
        a6 += wR * __uint_as_float(v1.w << 16);
        a7 += wR * __uint_as_float(v1.w & 0xffff0000u);
    }
    uint4 o;
    o.x = pkbf(a0, a1); o.y = pkbf(a2, a3);
    o.z = pkbf(a4, a5); o.w = pkbf(a6, a7);
    *(uint4*)(outbf + (size_t)bq * 256 + h2 * 32 + d4 * 8) = o;
}

// ================ fused residual-add + LayerNorm: wave per row ================
template <bool ABF, bool OF32>
__global__ __launch_bounds__(256) void add_ln(
    const void* __restrict__ ap, const ushort* __restrict__ bp,
    const float* __restrict__ g, const float* __restrict__ be,
    void* __restrict__ op)
{
    const int row = blockIdx.x * 4 + (threadIdx.x >> 6);
    if (row >= BL_C) return;
    const int ln = threadIdx.x & 63;
    const size_t base = (size_t)row * 256 + ln * 4;

    float x[4];
    if (ABF) {
        ushort4 a4 = *(const ushort4*)((const ushort*)ap + base);
        x[0] = bf2f(a4.x); x[1] = bf2f(a4.y); x[2] = bf2f(a4.z); x[3] = bf2f(a4.w);
    } else {
        float4 a4 = *(const float4*)((const float*)ap + base);
        x[0] = a4.x; x[1] = a4.y; x[2] = a4.z; x[3] = a4.w;
    }
    ushort4 b4 = *(const ushort4*)(bp + base);
    x[0] += bf2f(b4.x); x[1] += bf2f(b4.y); x[2] += bf2f(b4.z); x[3] += bf2f(b4.w);

    float s = x[0] + x[1] + x[2] + x[3];
    #pragma unroll
    for (int o = 32; o >= 1; o >>= 1) s += __shfl_xor(s, o, 64);
    const float mean = s * (1.f / 256.f);
    float d0 = x[0] - mean, d1 = x[1] - mean, d2 = x[2] - mean, d3 = x[3] - mean;
    float ss = d0 * d0 + d1 * d1 + d2 * d2 + d3 * d3;
    #pragma unroll
    for (int o = 32; o >= 1; o >>= 1) ss += __shfl_xor(ss, o, 64);
    const float rs = rsqrtf(ss * (1.f / 256.f) + 1e-5f);

    float4 gv = *(const float4*)(g + ln * 4);
    float4 bv = *(const float4*)(be + ln * 4);
    float o0 = d0 * rs * gv.x + bv.x;
    float o1 = d1 * rs * gv.y + bv.y;
    float o2 = d2 * rs * gv.z + bv.z;
    float o3 = d3 * rs * gv.w + bv.w;

    if (OF32) {
        *(float4*)((float*)op + base) = make_float4(o0, o1, o2, o3);
    } else {
        ushort4 st;
        st.x = f2bf(o0); st.y = f2bf(o1); st.z = f2bf(o2); st.w = f2bf(o3);
        *(ushort4*)((ushort*)op + base) = st;
    }
}

extern "C" void kernel_launch(void* const* d_in, const int* in_sizes, int n_in,
                              void* d_out, int out_size, void* d_ws, size_t ws_size,
                              hipStream_t stream) {
    const float* src    = (const float*)d_in[0];
    const float* pos    = (const float*)d_in[1];
    const float* refpts = (const float*)d_in[2];
    const float* W_off  = (const float*)d_in[5];
    const float* b_off  = (const float*)d_in[6];
    const float* W_attn = (const float*)d_in[7];
    const float* b_attn = (const float*)d_in[8];
    const float* W_val  = (const float*)d_in[9];
    const float* b_val  = (const float*)d_in[10];
    const float* W_out  = (const float*)d_in[11];
    const float* b_out  = (const float*)d_in[12];
    const float* W1     = (const float*)d_in[13];
    const float* b1     = (const float*)d_in[14];
    const float* W2     = (const float*)d_in[15];
    const float* b2     = (const float*)d_in[16];
    const float* g1     = (const float*)d_in[17];
    const float* be1    = (const float*)d_in[18];
    const float* g2     = (const float*)d_in[19];
    const float* be2    = (const float*)d_in[20];
    float* out = (float*)d_out;
    (void)in_sizes; (void)n_in; (void)out_size; (void)ws_size;

    const int BL = BL_C;
    char* ws = (char*)d_ws;
    const size_t HB  = (size_t)BL * 256 * 2;     // 20.68 MB
    const size_t OAB = (size_t)BL * 384 * 2;     // 31.02 MB

    // regions: A:[q -> x] B:[val] C:[oa] D:[ao] D2:[src2] E:[src_bf -> ffn2]
    ushort* q_bf    = (ushort*)(ws);                       // A
    ushort* x_bf    = (ushort*)(ws);                       // A (q dead after G2)
    ushort* val_bf  = (ushort*)(ws + HB);                  // B
    ushort* oa_bf   = (ushort*)(ws + 2 * HB);              // C
    ushort* ao_bf   = (ushort*)(ws + 2 * HB + OAB);        // D
    ushort* src2_bf = (ushort*)(ws + 3 * HB + OAB);        // D2
    ushort* srcb_bf = (ushort*)(ws + 4 * HB + OAB);        // E
    ushort* ffn2_bf = srcb_bf;                             // E (src_bf dead after LN1)
    ushort* mid_bf  = val_bf;                              // overlays B,C,D,D2 (93 MB)
    char*   wts     = ws + 5 * HB + OAB;
    ushort* Tval = (ushort*)(wts);               // 256x256
    ushort* Toa  = Tval + 256 * 256;             // 384x256
    ushort* Tout = Toa + 384 * 256;              // 256x256
    ushort* TW1  = Tout + 256 * 256;             // 1024x256
    ushort* TW2  = TW1 + 1024 * 256;             // 256x1024
    float*  boa  = (float*)(TW2 + 256 * 1024);   // 384

    dim3 blk(256);
    const int MT = (BL + 127) / 128;   // 316

    // 1) all prep (weights + q + src_bf)
    prep_all<<<dim3(738 + 1024), blk, 0, stream>>>(
        src, pos, W_val, W_off, W_attn, W_out, W1, W2, b_off, b_attn,
        Tval, Toa, Tout, TW1, TW2, boa, q_bf, srcb_bf);

    // 2) G1: value = src @ Wv + bv
    gemm_bs<false><<<dim3(MT * 4), blk, 0, stream>>>(
        srcb_bf, Tval, b_val, val_bf, BL, 256, 256, 4, MT * 4);
    // 3) G2: [off|attn] = q @ [Wo|Wa] + [bo|ba]
    gemm_bs<false><<<dim3(MT * 6), blk, 0, stream>>>(
        q_bf, Toa, boa, oa_bf, BL, 384, 256, 6, MT * 6);

    // 4) sampling -> ao
    sample_kernel<<<dim3((BL + 7) / 8), blk, 0, stream>>>(val_bf, oa_bf, refpts, ao_bf);

    // 5) G3: src2 = ao @ Wout + b_out
    gemm_bs<false><<<dim3(MT * 4), blk, 0, stream>>>(
        ao_bf, Tout, b_out, src2_bf, BL, 256, 256, 4, MT * 4);

    // 6) LN1: x = LN(src + src2)  (bf16 src residual)
    add_ln<true, false><<<dim3((BL + 3) / 4), blk, 0, stream>>>(
        srcb_bf, src2_bf, g1, be1, x_bf);

    // 7) G4: mid = relu(x @ W1 + b1)   (mid overlays val/oa/ao/src2)
    gemm_bs<true><<<dim3(MT * 16), blk, 0, stream>>>(
        x_bf, TW1, b1, mid_bf, BL, 1024, 256, 16, MT * 16);

    // 8) G5: ffn2 = mid @ W2 + b2   (overlays src_bf)
    gemm_bs<false><<<dim3(MT * 4), blk, 0, stream>>>(
        mid_bf, TW2, b2, ffn2_bf, BL, 256, 1024, 4, MT * 4);

    // 9) LN2: out = LN(x + ffn2) -> f32  (x is bf16!)
    add_ln<true, true><<<dim3((BL + 3) / 4), blk, 0, stream>>>(
        x_bf, ffn2_bf, g2, be2, out);
}